// Round 12
// baseline (813.292 us; speedup 1.0000x reference)
//
#include <hip/hip_runtime.h>

#define NN 100000
#define NE 1600000
#define HID 128
#define HEADS 4
#define CH 32
#define IN_DIM 257
#define CHK 64   // edges per LDS chunk in gather
#define NTP 128  // nodes per projection block
#define KC 32    // K-chunk in projection
#define XST (NTP + 4)  // padded xt row stride (132 floats)

// ==================== fused node projection + attention scalars ====================
// xt transposed [k][node] (padded stride 132), staged via COALESCED per-lane global loads
// + transposed ds_write_b32 (register transpose). wt [k][col] staged via global_load_lds
// width-16. 256 threads = 16 mg (8 nodes) x 16 cg (cols {cg*4, 64+cg*4}).
template <bool VEC4>
__global__ __launch_bounds__(256, 2) void node_proj_att(const float* __restrict__ X,
                                                        const float* __restrict__ W,
                                                        const float* __restrict__ att_src,
                                                        const float* __restrict__ att_dst,
                                                        float* __restrict__ XS,
                                                        float* __restrict__ asrc,
                                                        float* __restrict__ adst,
                                                        int K, long long maxx, long long maxw) {
    __shared__ float xt[2][KC][XST];  // transposed: [k][node]
    __shared__ float wt[2][KC][HID];
    int tid = threadIdx.x;
    int lane = tid & 63;
    int wv = tid >> 6;  // wave 0..3
    int block0 = blockIdx.x * NTP;
    int cg = tid & 15;
    int c0a = cg * 4, c0b = 64 + cg * 4;
    int mg = tid >> 4;  // 0..15
    int mbase = mg * 8;
    int nchunk = (K + KC - 1) / KC;

    float4 aA[8], aB[8];
#pragma unroll
    for (int m = 0; m < 8; ++m) {
        aA[m] = make_float4(0.f, 0.f, 0.f, 0.f);
        aB[m] = make_float4(0.f, 0.f, 0.f, 0.f);
    }

    float xreg[16];

    auto loadX = [&](int k0) {
        if (VEC4) {
#pragma unroll
            for (int i = 0; i < 4; ++i) {
                int row = wv * 32 + i * 8 + (lane >> 3);
                int k = (lane & 7) * 4;
                long long src = (long long)(block0 + row) * K + k0 + k;
                if (src > maxx - 3) src = maxx - 3;
                float4 v = *(const float4*)&X[src];
                xreg[i * 4 + 0] = v.x; xreg[i * 4 + 1] = v.y;
                xreg[i * 4 + 2] = v.z; xreg[i * 4 + 3] = v.w;
            }
        } else {
#pragma unroll
            for (int i = 0; i < 16; ++i) {
                int row = wv * 32 + i * 2 + (lane >> 5);
                long long src = (long long)(block0 + row) * K + k0 + (lane & 31);
                if (src > maxx) src = maxx;
                xreg[i] = X[src];
            }
        }
    };
    auto writeX = [&](int buf) {
        if (VEC4) {
#pragma unroll
            for (int i = 0; i < 4; ++i) {
                int row = wv * 32 + i * 8 + (lane >> 3);
                int k = (lane & 7) * 4;
#pragma unroll
                for (int j = 0; j < 4; ++j) xt[buf][k + j][row] = xreg[i * 4 + j];
            }
        } else {
#pragma unroll
            for (int i = 0; i < 16; ++i) {
                int row = wv * 32 + i * 2 + (lane >> 5);
                xt[buf][lane & 31][row] = xreg[i];
            }
        }
    };
    auto stageW = [&](int buf, int k0) {
#pragma unroll
        for (int i = 0; i < 4; ++i) {
            int idx = wv * 4 + i;  // 0..15, each instr covers 2 k-rows (1024B linear)
            long long src = (long long)(k0 + idx * 2) * HID + lane * 4;
            if (src > maxw - 3) src = maxw - 3;
            __builtin_amdgcn_global_load_lds(
                (const __attribute__((address_space(1))) void*)(W + src),
                (__attribute__((address_space(3))) void*)&wt[buf][idx * 2][0], 16, 0, 0);
        }
    };

    // prologue
    loadX(0);
    stageW(0, 0);
    asm volatile("s_waitcnt vmcnt(0)" ::: "memory");
    writeX(0);
    __syncthreads();

#define ROW8(m, xs)                                                              \
    aA[m].x += (xs)*w0.x; aA[m].y += (xs)*w0.y; aA[m].z += (xs)*w0.z; aA[m].w += (xs)*w0.w; \
    aB[m].x += (xs)*w1.x; aB[m].y += (xs)*w1.y; aB[m].z += (xs)*w1.z; aB[m].w += (xs)*w1.w;

    for (int c = 0; c < nchunk; ++c) {
        int k0 = c * KC;
        int cur = c & 1;
        bool more = (c + 1 < nchunk);
        if (more) { loadX(k0 + KC); stageW(cur ^ 1, k0 + KC); }
        int kc = min(KC, K - k0);
#pragma unroll 1
        for (int kk = 0; kk < kc; ++kk) {
            float4 x0 = *(const float4*)&xt[cur][kk][mbase];
            float4 x1 = *(const float4*)&xt[cur][kk][mbase + 4];
            float4 w0 = *(const float4*)&wt[cur][kk][c0a];
            float4 w1 = *(const float4*)&wt[cur][kk][c0b];
            ROW8(0, x0.x) ROW8(1, x0.y) ROW8(2, x0.z) ROW8(3, x0.w)
            ROW8(4, x1.x) ROW8(5, x1.y) ROW8(6, x1.z) ROW8(7, x1.w)
        }
        if (more) {
            asm volatile("s_waitcnt vmcnt(0)" ::: "memory");
            writeX(cur ^ 1);
        }
        __syncthreads();
    }
#undef ROW8

    // epilogue: write XS + fused per-head attention dots.
    float4 ava = *(const float4*)&att_src[c0a];
    float4 avb = *(const float4*)&att_src[c0b];
    float4 bva = *(const float4*)&att_dst[c0a];
    float4 bvb = *(const float4*)&att_dst[c0b];
    int hA = cg >> 3, hB = 2 + (cg >> 3);
#pragma unroll
    for (int m = 0; m < 8; ++m) {
        int node = block0 + mbase + m;
        float sA = aA[m].x * ava.x + aA[m].y * ava.y + aA[m].z * ava.z + aA[m].w * ava.w;
        float sB = aB[m].x * avb.x + aB[m].y * avb.y + aB[m].z * avb.z + aB[m].w * avb.w;
        float dA = aA[m].x * bva.x + aA[m].y * bva.y + aA[m].z * bva.z + aA[m].w * bva.w;
        float dB = aB[m].x * bvb.x + aB[m].y * bvb.y + aB[m].z * bvb.z + aB[m].w * bvb.w;
        sA += __shfl_xor(sA, 1); sB += __shfl_xor(sB, 1);
        dA += __shfl_xor(dA, 1); dB += __shfl_xor(dB, 1);
        sA += __shfl_xor(sA, 2); sB += __shfl_xor(sB, 2);
        dA += __shfl_xor(dA, 2); dB += __shfl_xor(dB, 2);
        sA += __shfl_xor(sA, 4); sB += __shfl_xor(sB, 4);
        dA += __shfl_xor(dA, 4); dB += __shfl_xor(dB, 4);
        if (node < NN) {
            *(float4*)&XS[(size_t)node * HID + c0a] = aA[m];
            *(float4*)&XS[(size_t)node * HID + c0b] = aB[m];
            if ((cg & 7) == 0) {
                asrc[node * 4 + hA] = sA;
                asrc[node * 4 + hB] = sB;
                adst[node * 4 + hA] = dA;
                adst[node * 4 + hB] = dB;
            }
        }
    }
}

// ---- ve[d,h] = sum_c We[d, h*CH+c] * att_edge[h,c]  (8x4) ----
__global__ void compute_ve(const float* __restrict__ We,
                           const float* __restrict__ att_edge,
                           float* __restrict__ ve) {
    int i = threadIdx.x;
    if (i >= 32) return;
    int d = i >> 2, h = i & 3;
    float s = 0.f;
    for (int c = 0; c < CH; ++c) s += We[d * HID + h * CH + c] * att_edge[h * CH + c];
    ve[i] = s;
}

// ---- edge_prep: aeP[idx][h] = eattr[eperm[idx]] . ve[:,h]  (contiguous write) ----
// Pays the 32B random eattr gather ONCE per layer; gather then reads aeP contiguously.
__global__ __launch_bounds__(256) void edge_prep(const int* __restrict__ eperm,
                                                 const float* __restrict__ eattr,
                                                 const float* __restrict__ ve,
                                                 float* __restrict__ aeP) {
    __shared__ float ves[32];
    if (threadIdx.x < 32) ves[threadIdx.x] = ve[threadIdx.x];
    __syncthreads();
    int idx = blockIdx.x * 256 + threadIdx.x;
    if (idx >= NE) return;
    int e = eperm[idx];
    float4 e0 = *(const float4*)&eattr[(size_t)e * 8];
    float4 e1 = *(const float4*)&eattr[(size_t)e * 8 + 4];
    float eav[8] = {e0.x, e0.y, e0.z, e0.w, e1.x, e1.y, e1.z, e1.w};
    float ae[4];
#pragma unroll
    for (int h = 0; h < 4; ++h) {
        float s = 0.f;
#pragma unroll
        for (int d = 0; d < 8; ++d) s += eav[d] * ves[d * 4 + h];
        ae[h] = s;
    }
    *(float4*)&aeP[(size_t)idx * 4] = make_float4(ae[0], ae[1], ae[2], ae[3]);
}

// ==================== CSR build ====================
__global__ __launch_bounds__(256) void k_deg(const int* __restrict__ ei, int* __restrict__ deg) {
    int e = blockIdx.x * 256 + threadIdx.x;
    if (e < NE) atomicAdd(&deg[ei[NE + e]], 1);
}

__global__ __launch_bounds__(256) void scan_local(const int* __restrict__ deg,
                                                  int* __restrict__ startv,
                                                  int* __restrict__ bsum) {
    __shared__ int sh[256];
    int t = threadIdx.x;
    int base = blockIdx.x * 1024 + t * 4;
    int v0 = 0, v1 = 0, v2 = 0, v3 = 0;
    if (base + 0 < NN) v0 = deg[base + 0];
    if (base + 1 < NN) v1 = deg[base + 1];
    if (base + 2 < NN) v2 = deg[base + 2];
    if (base + 3 < NN) v3 = deg[base + 3];
    int s1 = v0 + v1, s2 = s1 + v2, s3 = s2 + v3;
    sh[t] = s3;
    __syncthreads();
    for (int off = 1; off < 256; off <<= 1) {
        int x = (t >= off) ? sh[t - off] : 0;
        __syncthreads();
        sh[t] += x;
        __syncthreads();
    }
    int thOff = sh[t] - s3;  // exclusive
    if (base + 0 < NN) startv[base + 0] = thOff;
    if (base + 1 < NN) startv[base + 1] = thOff + v0;
    if (base + 2 < NN) startv[base + 2] = thOff + s1;
    if (base + 3 < NN) startv[base + 3] = thOff + s2;
    if (t == 255) bsum[blockIdx.x] = sh[255];
}

__global__ __launch_bounds__(256) void scan_bsum(int* __restrict__ bsum, int nb) {
    __shared__ int sh[256];
    int t = threadIdx.x;
    int v = (t < nb) ? bsum[t] : 0;
    sh[t] = v;
    __syncthreads();
    for (int off = 1; off < 256; off <<= 1) {
        int x = (t >= off) ? sh[t - off] : 0;
        __syncthreads();
        sh[t] += x;
        __syncthreads();
    }
    if (t < nb) bsum[t] = sh[t] - v;  // exclusive
}

__global__ __launch_bounds__(256) void scan_add(int* __restrict__ startv,
                                                const int* __restrict__ bsum) {
    int i = blockIdx.x * 256 + threadIdx.x;
    if (i < NN) startv[i] += bsum[i >> 10];
}

__global__ __launch_bounds__(256) void k_scatter(const int* __restrict__ ei,
                                                 const int* __restrict__ startv,
                                                 int* __restrict__ cursor,
                                                 int* __restrict__ eperm,
                                                 int* __restrict__ srcperm) {
    int e = blockIdx.x * 256 + threadIdx.x;
    if (e >= NE) return;
    int d = ei[NE + e];
    int pos = startv[d] + atomicAdd(&cursor[d], 1);
    eperm[pos] = e;
    srcperm[pos] = ei[e];
}

// ==================== fused gather: softmax (no-max) + aggregate + bias + relu ====
// one wave per dst node. Stage reads srcperm (contig 4B) + aeP (contig 16B) +
// asrc[s] (16B gather, 1.6MB array = L2-resident); p = exp(leaky(as+ad+ae)).
// Sweep keeps 8 XS row-gathers (contiguous 512B each) in flight.
__global__ __launch_bounds__(256) void gat_gather(const int* __restrict__ startv,
                                                  const int* __restrict__ deg,
                                                  const int* __restrict__ srcperm,
                                                  const float* __restrict__ aeP,
                                                  const float* __restrict__ asrc,
                                                  const float* __restrict__ adst,
                                                  const float* __restrict__ XS,
                                                  const float* __restrict__ bias,
                                                  float* __restrict__ OUT) {
    __shared__ float s_p[4][CHK * 4];
    __shared__ int s_src[4][CHK];
    int w = threadIdx.x >> 6;
    int wid = blockIdx.x * 4 + w;
    if (wid >= NN) return;
    int lane = threadIdx.x & 63;
    int s0 = startv[wid];
    int dg = deg[wid];
    float4 ad4 = *(const float4*)&adst[wid * 4];
    int h = lane >> 4;
    int c0 = lane * 2;

    float denom = 0.f, acc0 = 0.f, acc1 = 0.f;

    for (int cb = 0; cb < dg; cb += CHK) {
        int cnt = min(CHK, dg - cb);
        // stage: src index + per-head p = exp(alpha) into LDS (wave-synchronous)
        for (int i = lane; i < cnt; i += 64) {
            int pos = s0 + cb + i;
            int s = srcperm[pos];
            s_src[w][i] = s;
            float4 ae = *(const float4*)&aeP[(size_t)pos * 4];
            float4 as4 = *(const float4*)&asrc[s * 4];
            float a0 = as4.x + ad4.x + ae.x;
            float a1 = as4.y + ad4.y + ae.y;
            float a2 = as4.z + ad4.z + ae.z;
            float a3 = as4.w + ad4.w + ae.w;
            a0 = (a0 > 0.f) ? a0 : 0.2f * a0;
            a1 = (a1 > 0.f) ? a1 : 0.2f * a1;
            a2 = (a2 > 0.f) ? a2 : 0.2f * a2;
            a3 = (a3 > 0.f) ? a3 : 0.2f * a3;
            *(float4*)&s_p[w][i * 4] =
                make_float4(__expf(a0), __expf(a1), __expf(a2), __expf(a3));
        }
        // accumulate sweep, 8 XS gathers in flight
        int j = 0;
        for (; j + 7 < cnt; j += 8) {
            int sv[8];
            float pv[8];
            float2 xv[8];
#pragma unroll
            for (int q = 0; q < 8; ++q) {
                sv[q] = s_src[w][j + q];
                pv[q] = s_p[w][(j + q) * 4 + h];
            }
#pragma unroll
            for (int q = 0; q < 8; ++q) xv[q] = *(const float2*)&XS[(size_t)sv[q] * HID + c0];
#pragma unroll
            for (int q = 0; q < 8; ++q) {
                denom += pv[q];
                acc0 += pv[q] * xv[q].x;
                acc1 += pv[q] * xv[q].y;
            }
        }
        for (; j + 3 < cnt; j += 4) {
            int sA = s_src[w][j], sB = s_src[w][j + 1], sC = s_src[w][j + 2], sD = s_src[w][j + 3];
            float pA = s_p[w][j * 4 + h], pB = s_p[w][(j + 1) * 4 + h];
            float pC = s_p[w][(j + 2) * 4 + h], pD = s_p[w][(j + 3) * 4 + h];
            float2 xA = *(const float2*)&XS[(size_t)sA * HID + c0];
            float2 xB = *(const float2*)&XS[(size_t)sB * HID + c0];
            float2 xC = *(const float2*)&XS[(size_t)sC * HID + c0];
            float2 xD = *(const float2*)&XS[(size_t)sD * HID + c0];
            denom += pA + pB + pC + pD;
            acc0 += pA * xA.x + pB * xB.x + pC * xC.x + pD * xD.x;
            acc1 += pA * xA.y + pB * xB.y + pC * xC.y + pD * xD.y;
        }
        for (; j < cnt; ++j) {
            int s = s_src[w][j];
            float p = s_p[w][j * 4 + h];
            float2 xv = *(const float2*)&XS[(size_t)s * HID + c0];
            denom += p;
            acc0 += p * xv.x;
            acc1 += p * xv.y;
        }
    }
    float inv = 1.f / (denom + 1e-16f);
    float2 bv = *(const float2*)&bias[c0];
    float o0 = fmaxf(acc0 * inv + bv.x, 0.f);
    float o1 = fmaxf(acc1 * inv + bv.y, 0.f);
    *(float2*)&OUT[(size_t)wid * HID + c0] = make_float2(o0, o1);
}

// ==================== pooling ====================
#define POOL_CHUNK 512
__global__ __launch_bounds__(256) void pool_kernel(const float* __restrict__ H,
                                                   const int* __restrict__ batch,
                                                   float* __restrict__ pooled,
                                                   float* __restrict__ counts) {
    __shared__ float tab[64 * HID];
    __shared__ float cnt[64];
    int tid = threadIdx.x;
    int n0 = blockIdx.x * POOL_CHUNK;
    int nmax = min(POOL_CHUNK, NN - n0);
    for (int i = tid; i < 64 * HID; i += 256) tab[i] = 0.f;
    if (tid < 64) cnt[tid] = 0.f;
    __syncthreads();
    for (int i = tid; i < nmax * HID; i += 256) {
        int n = n0 + (i >> 7), c = i & 127;
        int g = batch[n];
        atomicAdd(&tab[g * HID + c], H[(long long)n * HID + c]);
    }
    for (int n = tid; n < nmax; n += 256) atomicAdd(&cnt[batch[n0 + n]], 1.f);
    __syncthreads();
    int gmin = batch[n0], gmax = batch[n0 + nmax - 1];
    int ng = gmax - gmin + 1;
    for (int i = tid; i < ng * HID; i += 256) {
        int g = gmin + (i >> 7), c = i & 127;
        atomicAdd(&pooled[g * HID + c], tab[g * HID + c]);
    }
    if (tid < ng) atomicAdd(&counts[gmin + tid], cnt[gmin + tid]);
}

// ==================== classifier ====================
__global__ __launch_bounds__(64) void classifier(const float* __restrict__ pooled,
                                                 const float* __restrict__ counts,
                                                 const float* __restrict__ Wc1,
                                                 const float* __restrict__ bc1,
                                                 const float* __restrict__ Wc2,
                                                 const float* __restrict__ bc2,
                                                 float* __restrict__ out) {
    __shared__ float pl[HID];
    __shared__ float z[64];
    int g = blockIdx.x, t = threadIdx.x;
    float inv = 1.f / fmaxf(counts[g], 1.f);
    pl[t] = pooled[g * HID + t] * inv;
    pl[t + 64] = pooled[g * HID + 64 + t] * inv;
    __syncthreads();
    float a = bc1[t];
    for (int k = 0; k < HID; ++k) a += pl[k] * Wc1[k * 64 + t];
    z[t] = fmaxf(a, 0.f);
    __syncthreads();
    if (t < 2) {
        float o = bc2[t];
        for (int j = 0; j < 64; ++j) o += z[j] * Wc2[j * 2 + t];
        out[g * 2 + t] = o;
    }
}

extern "C" void kernel_launch(void* const* d_in, const int* in_sizes, int n_in,
                              void* d_out, int out_size, void* d_ws, size_t ws_size,
                              hipStream_t stream) {
    const float* x = (const float*)d_in[0];
    const int* ei = (const int*)d_in[1];
    const float* eattr = (const float*)d_in[2];
    const int* batch = (const int*)d_in[3];
    const float* W1 = (const float*)d_in[4];
    const float* att_src1 = (const float*)d_in[5];
    const float* att_dst1 = (const float*)d_in[6];
    const float* We1 = (const float*)d_in[7];
    const float* att_edge1 = (const float*)d_in[8];
    const float* b1 = (const float*)d_in[9];
    const float* W2 = (const float*)d_in[10];
    const float* att_src2 = (const float*)d_in[11];
    const float* att_dst2 = (const float*)d_in[12];
    const float* We2 = (const float*)d_in[13];
    const float* att_edge2 = (const float*)d_in[14];
    const float* b2 = (const float*)d_in[15];
    const float* Wc1 = (const float*)d_in[16];
    const float* bc1 = (const float*)d_in[17];
    const float* Wc2 = (const float*)d_in[18];
    const float* bc2 = (const float*)d_in[19];
    float* out = (float*)d_out;

    // workspace layout (floats then ints; deg+cursor adjacent for one memset)
    float* A = (float*)d_ws;                        // xs buffer [N,128]
    float* B = A + (size_t)NN * HID;                // h buffer [N,128]
    float* asrc = B + (size_t)NN * HID;             // [N,4]
    float* adst = asrc + (size_t)NN * 4;            // [N,4]
    float* ve = adst + (size_t)NN * 4;              // [32]
    float* pooled = ve + 32;                        // [64,128]
    float* counts = pooled + 64 * HID;              // [64]
    float* aeP = counts + 64;                       // [E,4] permuted a_edge (reused per layer)
    int* deg = (int*)(aeP + (size_t)NE * 4);        // [N]
    int* cursor = deg + NN;                         // [N]
    int* startv = cursor + NN;                      // [N]
    int* bsum = startv + NN;                        // [256]
    int* eperm = bsum + 256;                        // [E]
    int* srcperm = eperm + NE;                      // [E]

    int gProj = (NN + NTP - 1) / NTP;  // 782
    int gE = (NE + 255) / 256;
    int gGat = (NN + 3) / 4;
    int nScanBlk = (NN + 1023) / 1024;  // 98

    // ===== CSR build (once per launch) =====
    hipMemsetAsync(deg, 0, (size_t)2 * NN * sizeof(int), stream);  // deg + cursor
    k_deg<<<gE, 256, 0, stream>>>(ei, deg);
    scan_local<<<nScanBlk, 256, 0, stream>>>(deg, startv, bsum);
    scan_bsum<<<1, 256, 0, stream>>>(bsum, nScanBlk);
    scan_add<<<(NN + 255) / 256, 256, 0, stream>>>(startv, bsum);
    k_scatter<<<gE, 256, 0, stream>>>(ei, startv, cursor, eperm, srcperm);

    // ===== layer 1 =====
    compute_ve<<<1, 32, 0, stream>>>(We1, att_edge1, ve);
    edge_prep<<<gE, 256, 0, stream>>>(eperm, eattr, ve, aeP);
    node_proj_att<false><<<gProj, 256, 0, stream>>>(x, W1, att_src1, att_dst1, A, asrc, adst,
                                                    IN_DIM, (long long)NN * IN_DIM - 1,
                                                    (long long)IN_DIM * HID - 1);
    gat_gather<<<gGat, 256, 0, stream>>>(startv, deg, srcperm, aeP, asrc, adst,
                                         A, b1, B);  // B = h1

    // ===== layer 2 =====
    compute_ve<<<1, 32, 0, stream>>>(We2, att_edge2, ve);
    edge_prep<<<gE, 256, 0, stream>>>(eperm, eattr, ve, aeP);
    node_proj_att<true><<<gProj, 256, 0, stream>>>(B, W2, att_src2, att_dst2, A, asrc, adst,
                                                   HID, (long long)NN * HID - 1,
                                                   (long long)HID * HID - 1);
    gat_gather<<<gGat, 256, 0, stream>>>(startv, deg, srcperm, aeP, asrc, adst,
                                         A, b2, B);  // B = h2

    // ===== pool + classify =====
    hipMemsetAsync(pooled, 0, (64 * HID + 64) * sizeof(float), stream);
    pool_kernel<<<(NN + POOL_CHUNK - 1) / POOL_CHUNK, 256, 0, stream>>>(B, batch, pooled, counts);
    classifier<<<64, 64, 0, stream>>>(pooled, counts, Wc1, bc1, Wc2, bc2, out);
}

// Round 13
// 800.623 us; speedup vs baseline: 1.0158x; 1.0158x over previous
//
#include <hip/hip_runtime.h>

#define NN 100000
#define NE 1600000
#define HID 128
#define HEADS 4
#define CH 32
#define IN_DIM 257
#define CHK 64   // edges per LDS chunk in gather
#define NTP 128  // nodes per projection block
#define KC 16    // K-chunk in projection
#define XST 133  // xt row stride: 133 mod 32 = 5 (coprime) -> conflict-free transposed writes

// ==================== fused node projection + attention scalars ====================
// xt transposed [k][node] (stride 133), staged via COALESCED per-lane global loads +
// transposed ds_write_b32. wt [k][col] staged via global_load_lds width-16.
// 256 threads = 16 mg (8 nodes) x 16 cg (cols {cg*4, 64+cg*4}).
// KC=16 -> 33.4KB LDS -> 4 blocks/CU (all 782 blocks co-resident).
template <bool VEC4>
__global__ __launch_bounds__(256, 4) void node_proj_att(const float* __restrict__ X,
                                                        const float* __restrict__ W,
                                                        const float* __restrict__ att_src,
                                                        const float* __restrict__ att_dst,
                                                        float* __restrict__ XS,
                                                        float* __restrict__ asrc,
                                                        float* __restrict__ adst,
                                                        int K, long long maxx, long long maxw) {
    __shared__ float xt[2][KC][XST];  // transposed: [k][node]
    __shared__ float wt[2][KC][HID];
    int tid = threadIdx.x;
    int lane = tid & 63;
    int wv = tid >> 6;  // wave 0..3
    int block0 = blockIdx.x * NTP;
    int cg = tid & 15;
    int c0a = cg * 4, c0b = 64 + cg * 4;
    int mg = tid >> 4;  // 0..15
    int mbase = mg * 8;
    int nchunk = (K + KC - 1) / KC;

    float4 aA[8], aB[8];
#pragma unroll
    for (int m = 0; m < 8; ++m) {
        aA[m] = make_float4(0.f, 0.f, 0.f, 0.f);
        aB[m] = make_float4(0.f, 0.f, 0.f, 0.f);
    }

    float xreg[8];

    // coalesced global load of next X chunk (128 rows x 16 cols) into registers
    auto loadX = [&](int k0) {
        if (VEC4) {
#pragma unroll
            for (int i = 0; i < 2; ++i) {
                int row = wv * 32 + i * 16 + (lane >> 2);
                int k = (lane & 3) * 4;
                long long src = (long long)(block0 + row) * K + k0 + k;
                if (src > maxx - 3) src = maxx - 3;
                float4 v = *(const float4*)&X[src];
                xreg[i * 4 + 0] = v.x; xreg[i * 4 + 1] = v.y;
                xreg[i * 4 + 2] = v.z; xreg[i * 4 + 3] = v.w;
            }
        } else {
#pragma unroll
            for (int i = 0; i < 8; ++i) {
                int row = wv * 32 + i * 4 + (lane >> 4);
                long long src = (long long)(block0 + row) * K + k0 + (lane & 15);
                if (src > maxx) src = maxx;
                xreg[i] = X[src];
            }
        }
    };
    // transposed LDS write of the register-staged chunk
    auto writeX = [&](int buf) {
        if (VEC4) {
#pragma unroll
            for (int i = 0; i < 2; ++i) {
                int row = wv * 32 + i * 16 + (lane >> 2);
                int k = (lane & 3) * 4;
#pragma unroll
                for (int j = 0; j < 4; ++j) xt[buf][k + j][row] = xreg[i * 4 + j];
            }
        } else {
#pragma unroll
            for (int i = 0; i < 8; ++i) {
                int row = wv * 32 + i * 4 + (lane >> 4);
                xt[buf][lane & 15][row] = xreg[i];
            }
        }
    };
    auto stageW = [&](int buf, int k0) {
#pragma unroll
        for (int i = 0; i < 2; ++i) {
            int idx = wv * 2 + i;  // 0..7, each instr covers 2 k-rows (1024B linear)
            long long src = (long long)(k0 + idx * 2) * HID + lane * 4;
            if (src > maxw - 3) src = maxw - 3;
            __builtin_amdgcn_global_load_lds(
                (const __attribute__((address_space(1))) void*)(W + src),
                (__attribute__((address_space(3))) void*)&wt[buf][idx * 2][0], 16, 0, 0);
        }
    };

    // prologue
    loadX(0);
    stageW(0, 0);
    asm volatile("s_waitcnt vmcnt(0)" ::: "memory");
    writeX(0);
    __syncthreads();

#define ROW8(m, xs)                                                              \
    aA[m].x += (xs)*w0.x; aA[m].y += (xs)*w0.y; aA[m].z += (xs)*w0.z; aA[m].w += (xs)*w0.w; \
    aB[m].x += (xs)*w1.x; aB[m].y += (xs)*w1.y; aB[m].z += (xs)*w1.z; aB[m].w += (xs)*w1.w;

    for (int c = 0; c < nchunk; ++c) {
        int k0 = c * KC;
        int cur = c & 1;
        bool more = (c + 1 < nchunk);
        if (more) { loadX(k0 + KC); stageW(cur ^ 1, k0 + KC); }
        int kc = min(KC, K - k0);
#pragma unroll 1
        for (int kk = 0; kk < kc; ++kk) {
            float4 x0 = *(const float4*)&xt[cur][kk][mbase];
            float4 x1 = *(const float4*)&xt[cur][kk][mbase + 4];
            float4 w0 = *(const float4*)&wt[cur][kk][c0a];
            float4 w1 = *(const float4*)&wt[cur][kk][c0b];
            ROW8(0, x0.x) ROW8(1, x0.y) ROW8(2, x0.z) ROW8(3, x0.w)
            ROW8(4, x1.x) ROW8(5, x1.y) ROW8(6, x1.z) ROW8(7, x1.w)
        }
        if (more) {
            asm volatile("s_waitcnt vmcnt(0)" ::: "memory");
            writeX(cur ^ 1);
        }
        __syncthreads();
    }
#undef ROW8

    // epilogue: write XS + fused per-head attention dots.
    float4 ava = *(const float4*)&att_src[c0a];
    float4 avb = *(const float4*)&att_src[c0b];
    float4 bva = *(const float4*)&att_dst[c0a];
    float4 bvb = *(const float4*)&att_dst[c0b];
    int hA = cg >> 3, hB = 2 + (cg >> 3);
#pragma unroll
    for (int m = 0; m < 8; ++m) {
        int node = block0 + mbase + m;
        float sA = aA[m].x * ava.x + aA[m].y * ava.y + aA[m].z * ava.z + aA[m].w * ava.w;
        float sB = aB[m].x * avb.x + aB[m].y * avb.y + aB[m].z * avb.z + aB[m].w * avb.w;
        float dA = aA[m].x * bva.x + aA[m].y * bva.y + aA[m].z * bva.z + aA[m].w * bva.w;
        float dB = aB[m].x * bvb.x + aB[m].y * bvb.y + aB[m].z * bvb.z + aB[m].w * bvb.w;
        sA += __shfl_xor(sA, 1); sB += __shfl_xor(sB, 1);
        dA += __shfl_xor(dA, 1); dB += __shfl_xor(dB, 1);
        sA += __shfl_xor(sA, 2); sB += __shfl_xor(sB, 2);
        dA += __shfl_xor(dA, 2); dB += __shfl_xor(dB, 2);
        sA += __shfl_xor(sA, 4); sB += __shfl_xor(sB, 4);
        dA += __shfl_xor(dA, 4); dB += __shfl_xor(dB, 4);
        if (node < NN) {
            *(float4*)&XS[(size_t)node * HID + c0a] = aA[m];
            *(float4*)&XS[(size_t)node * HID + c0b] = aB[m];
            if ((cg & 7) == 0) {
                asrc[node * 4 + hA] = sA;
                asrc[node * 4 + hB] = sB;
                adst[node * 4 + hA] = dA;
                adst[node * 4 + hB] = dB;
            }
        }
    }
}

// ---- ve[d,h] = sum_c We[d, h*CH+c] * att_edge[h,c]  (8x4) ----
__global__ void compute_ve(const float* __restrict__ We,
                           const float* __restrict__ att_edge,
                           float* __restrict__ ve) {
    int i = threadIdx.x;
    if (i >= 32) return;
    int d = i >> 2, h = i & 3;
    float s = 0.f;
    for (int c = 0; c < CH; ++c) s += We[d * HID + h * CH + c] * att_edge[h * CH + c];
    ve[i] = s;
}

// ---- edge_prep: aeP[idx][h] = eattr[eperm[idx]] . ve[:,h]  (contiguous write) ----
__global__ __launch_bounds__(256) void edge_prep(const int* __restrict__ eperm,
                                                 const float* __restrict__ eattr,
                                                 const float* __restrict__ ve,
                                                 float* __restrict__ aeP) {
    __shared__ float ves[32];
    if (threadIdx.x < 32) ves[threadIdx.x] = ve[threadIdx.x];
    __syncthreads();
    int idx = blockIdx.x * 256 + threadIdx.x;
    if (idx >= NE) return;
    int e = eperm[idx];
    float4 e0 = *(const float4*)&eattr[(size_t)e * 8];
    float4 e1 = *(const float4*)&eattr[(size_t)e * 8 + 4];
    float eav[8] = {e0.x, e0.y, e0.z, e0.w, e1.x, e1.y, e1.z, e1.w};
    float ae[4];
#pragma unroll
    for (int h = 0; h < 4; ++h) {
        float s = 0.f;
#pragma unroll
        for (int d = 0; d < 8; ++d) s += eav[d] * ves[d * 4 + h];
        ae[h] = s;
    }
    *(float4*)&aeP[(size_t)idx * 4] = make_float4(ae[0], ae[1], ae[2], ae[3]);
}

// ==================== CSR build ====================
__global__ __launch_bounds__(256) void k_deg(const int* __restrict__ ei, int* __restrict__ deg) {
    int e = blockIdx.x * 256 + threadIdx.x;
    if (e < NE) atomicAdd(&deg[ei[NE + e]], 1);
}

__global__ __launch_bounds__(256) void scan_local(const int* __restrict__ deg,
                                                  int* __restrict__ startv,
                                                  int* __restrict__ bsum) {
    __shared__ int sh[256];
    int t = threadIdx.x;
    int base = blockIdx.x * 1024 + t * 4;
    int v0 = 0, v1 = 0, v2 = 0, v3 = 0;
    if (base + 0 < NN) v0 = deg[base + 0];
    if (base + 1 < NN) v1 = deg[base + 1];
    if (base + 2 < NN) v2 = deg[base + 2];
    if (base + 3 < NN) v3 = deg[base + 3];
    int s1 = v0 + v1, s2 = s1 + v2, s3 = s2 + v3;
    sh[t] = s3;
    __syncthreads();
    for (int off = 1; off < 256; off <<= 1) {
        int x = (t >= off) ? sh[t - off] : 0;
        __syncthreads();
        sh[t] += x;
        __syncthreads();
    }
    int thOff = sh[t] - s3;  // exclusive
    if (base + 0 < NN) startv[base + 0] = thOff;
    if (base + 1 < NN) startv[base + 1] = thOff + v0;
    if (base + 2 < NN) startv[base + 2] = thOff + s1;
    if (base + 3 < NN) startv[base + 3] = thOff + s2;
    if (t == 255) bsum[blockIdx.x] = sh[255];
}

__global__ __launch_bounds__(256) void scan_bsum(int* __restrict__ bsum, int nb) {
    __shared__ int sh[256];
    int t = threadIdx.x;
    int v = (t < nb) ? bsum[t] : 0;
    sh[t] = v;
    __syncthreads();
    for (int off = 1; off < 256; off <<= 1) {
        int x = (t >= off) ? sh[t - off] : 0;
        __syncthreads();
        sh[t] += x;
        __syncthreads();
    }
    if (t < nb) bsum[t] = sh[t] - v;  // exclusive
}

__global__ __launch_bounds__(256) void scan_add(int* __restrict__ startv,
                                                const int* __restrict__ bsum) {
    int i = blockIdx.x * 256 + threadIdx.x;
    if (i < NN) startv[i] += bsum[i >> 10];
}

__global__ __launch_bounds__(256) void k_scatter(const int* __restrict__ ei,
                                                 const int* __restrict__ startv,
                                                 int* __restrict__ cursor,
                                                 int* __restrict__ eperm,
                                                 int* __restrict__ srcperm) {
    int e = blockIdx.x * 256 + threadIdx.x;
    if (e >= NE) return;
    int d = ei[NE + e];
    int pos = startv[d] + atomicAdd(&cursor[d], 1);
    eperm[pos] = e;
    srcperm[pos] = ei[e];
}

// ==================== fused gather: softmax (no-max) + aggregate + bias + relu ====
__global__ __launch_bounds__(256) void gat_gather(const int* __restrict__ startv,
                                                  const int* __restrict__ deg,
                                                  const int* __restrict__ srcperm,
                                                  const float* __restrict__ aeP,
                                                  const float* __restrict__ asrc,
                                                  const float* __restrict__ adst,
                                                  const float* __restrict__ XS,
                                                  const float* __restrict__ bias,
                                                  float* __restrict__ OUT) {
    __shared__ float s_p[4][CHK * 4];
    __shared__ int s_src[4][CHK];
    int w = threadIdx.x >> 6;
    int wid = blockIdx.x * 4 + w;
    if (wid >= NN) return;
    int lane = threadIdx.x & 63;
    int s0 = startv[wid];
    int dg = deg[wid];
    float4 ad4 = *(const float4*)&adst[wid * 4];
    int h = lane >> 4;
    int c0 = lane * 2;

    float denom = 0.f, acc0 = 0.f, acc1 = 0.f;

    for (int cb = 0; cb < dg; cb += CHK) {
        int cnt = min(CHK, dg - cb);
        for (int i = lane; i < cnt; i += 64) {
            int pos = s0 + cb + i;
            int s = srcperm[pos];
            s_src[w][i] = s;
            float4 ae = *(const float4*)&aeP[(size_t)pos * 4];
            float4 as4 = *(const float4*)&asrc[s * 4];
            float a0 = as4.x + ad4.x + ae.x;
            float a1 = as4.y + ad4.y + ae.y;
            float a2 = as4.z + ad4.z + ae.z;
            float a3 = as4.w + ad4.w + ae.w;
            a0 = (a0 > 0.f) ? a0 : 0.2f * a0;
            a1 = (a1 > 0.f) ? a1 : 0.2f * a1;
            a2 = (a2 > 0.f) ? a2 : 0.2f * a2;
            a3 = (a3 > 0.f) ? a3 : 0.2f * a3;
            *(float4*)&s_p[w][i * 4] =
                make_float4(__expf(a0), __expf(a1), __expf(a2), __expf(a3));
        }
        int j = 0;
        for (; j + 7 < cnt; j += 8) {
            int sv[8];
            float pv[8];
            float2 xv[8];
#pragma unroll
            for (int q = 0; q < 8; ++q) {
                sv[q] = s_src[w][j + q];
                pv[q] = s_p[w][(j + q) * 4 + h];
            }
#pragma unroll
            for (int q = 0; q < 8; ++q) xv[q] = *(const float2*)&XS[(size_t)sv[q] * HID + c0];
#pragma unroll
            for (int q = 0; q < 8; ++q) {
                denom += pv[q];
                acc0 += pv[q] * xv[q].x;
                acc1 += pv[q] * xv[q].y;
            }
        }
        for (; j + 3 < cnt; j += 4) {
            int sA = s_src[w][j], sB = s_src[w][j + 1], sC = s_src[w][j + 2], sD = s_src[w][j + 3];
            float pA = s_p[w][j * 4 + h], pB = s_p[w][(j + 1) * 4 + h];
            float pC = s_p[w][(j + 2) * 4 + h], pD = s_p[w][(j + 3) * 4 + h];
            float2 xA = *(const float2*)&XS[(size_t)sA * HID + c0];
            float2 xB = *(const float2*)&XS[(size_t)sB * HID + c0];
            float2 xC = *(const float2*)&XS[(size_t)sC * HID + c0];
            float2 xD = *(const float2*)&XS[(size_t)sD * HID + c0];
            denom += pA + pB + pC + pD;
            acc0 += pA * xA.x + pB * xB.x + pC * xC.x + pD * xD.x;
            acc1 += pA * xA.y + pB * xB.y + pC * xC.y + pD * xD.y;
        }
        for (; j < cnt; ++j) {
            int s = s_src[w][j];
            float p = s_p[w][j * 4 + h];
            float2 xv = *(const float2*)&XS[(size_t)s * HID + c0];
            denom += p;
            acc0 += p * xv.x;
            acc1 += p * xv.y;
        }
    }
    float inv = 1.f / (denom + 1e-16f);
    float2 bv = *(const float2*)&bias[c0];
    float o0 = fmaxf(acc0 * inv + bv.x, 0.f);
    float o1 = fmaxf(acc1 * inv + bv.y, 0.f);
    *(float2*)&OUT[(size_t)wid * HID + c0] = make_float2(o0, o1);
}

// ==================== pooling ====================
#define POOL_CHUNK 512
__global__ __launch_bounds__(256) void pool_kernel(const float* __restrict__ H,
                                                   const int* __restrict__ batch,
                                                   float* __restrict__ pooled,
                                                   float* __restrict__ counts) {
    __shared__ float tab[64 * HID];
    __shared__ float cnt[64];
    int tid = threadIdx.x;
    int n0 = blockIdx.x * POOL_CHUNK;
    int nmax = min(POOL_CHUNK, NN - n0);
    for (int i = tid; i < 64 * HID; i += 256) tab[i] = 0.f;
    if (tid < 64) cnt[tid] = 0.f;
    __syncthreads();
    for (int i = tid; i < nmax * HID; i += 256) {
        int n = n0 + (i >> 7), c = i & 127;
        int g = batch[n];
        atomicAdd(&tab[g * HID + c], H[(long long)n * HID + c]);
    }
    for (int n = tid; n < nmax; n += 256) atomicAdd(&cnt[batch[n0 + n]], 1.f);
    __syncthreads();
    int gmin = batch[n0], gmax = batch[n0 + nmax - 1];
    int ng = gmax - gmin + 1;
    for (int i = tid; i < ng * HID; i += 256) {
        int g = gmin + (i >> 7), c = i & 127;
        atomicAdd(&pooled[g * HID + c], tab[g * HID + c]);
    }
    if (tid < ng) atomicAdd(&counts[gmin + tid], cnt[gmin + tid]);
}

// ==================== classifier ====================
__global__ __launch_bounds__(64) void classifier(const float* __restrict__ pooled,
                                                 const float* __restrict__ counts,
                                                 const float* __restrict__ Wc1,
                                                 const float* __restrict__ bc1,
                                                 const float* __restrict__ Wc2,
                                                 const float* __restrict__ bc2,
                                                 float* __restrict__ out) {
    __shared__ float pl[HID];
    __shared__ float z[64];
    int g = blockIdx.x, t = threadIdx.x;
    float inv = 1.f / fmaxf(counts[g], 1.f);
    pl[t] = pooled[g * HID + t] * inv;
    pl[t + 64] = pooled[g * HID + 64 + t] * inv;
    __syncthreads();
    float a = bc1[t];
    for (int k = 0; k < HID; ++k) a += pl[k] * Wc1[k * 64 + t];
    z[t] = fmaxf(a, 0.f);
    __syncthreads();
    if (t < 2) {
        float o = bc2[t];
        for (int j = 0; j < 64; ++j) o += z[j] * Wc2[j * 2 + t];
        out[g * 2 + t] = o;
    }
}

extern "C" void kernel_launch(void* const* d_in, const int* in_sizes, int n_in,
                              void* d_out, int out_size, void* d_ws, size_t ws_size,
                              hipStream_t stream) {
    const float* x = (const float*)d_in[0];
    const int* ei = (const int*)d_in[1];
    const float* eattr = (const float*)d_in[2];
    const int* batch = (const int*)d_in[3];
    const float* W1 = (const float*)d_in[4];
    const float* att_src1 = (const float*)d_in[5];
    const float* att_dst1 = (const float*)d_in[6];
    const float* We1 = (const float*)d_in[7];
    const float* att_edge1 = (const float*)d_in[8];
    const float* b1 = (const float*)d_in[9];
    const float* W2 = (const float*)d_in[10];
    const float* att_src2 = (const float*)d_in[11];
    const float* att_dst2 = (const float*)d_in[12];
    const float* We2 = (const float*)d_in[13];
    const float* att_edge2 = (const float*)d_in[14];
    const float* b2 = (const float*)d_in[15];
    const float* Wc1 = (const float*)d_in[16];
    const float* bc1 = (const float*)d_in[17];
    const float* Wc2 = (const float*)d_in[18];
    const float* bc2 = (const float*)d_in[19];
    float* out = (float*)d_out;

    // workspace layout (floats then ints; deg+cursor adjacent for one memset)
    float* A = (float*)d_ws;                        // xs buffer [N,128]
    float* B = A + (size_t)NN * HID;                // h buffer [N,128]
    float* asrc = B + (size_t)NN * HID;             // [N,4]
    float* adst = asrc + (size_t)NN * 4;            // [N,4]
    float* ve = adst + (size_t)NN * 4;              // [32]
    float* pooled = ve + 32;                        // [64,128]
    float* counts = pooled + 64 * HID;              // [64]
    float* aeP = counts + 64;                       // [E,4] permuted a_edge (reused per layer)
    int* deg = (int*)(aeP + (size_t)NE * 4);        // [N]
    int* cursor = deg + NN;                         // [N]
    int* startv = cursor + NN;                      // [N]
    int* bsum = startv + NN;                        // [256]
    int* eperm = bsum + 256;                        // [E]
    int* srcperm = eperm + NE;                      // [E]

    int gProj = (NN + NTP - 1) / NTP;  // 782
    int gE = (NE + 255) / 256;
    int gGat = (NN + 3) / 4;
    int nScanBlk = (NN + 1023) / 1024;  // 98

    // ===== CSR build (once per launch) =====
    hipMemsetAsync(deg, 0, (size_t)2 * NN * sizeof(int), stream);  // deg + cursor
    k_deg<<<gE, 256, 0, stream>>>(ei, deg);
    scan_local<<<nScanBlk, 256, 0, stream>>>(deg, startv, bsum);
    scan_bsum<<<1, 256, 0, stream>>>(bsum, nScanBlk);
    scan_add<<<(NN + 255) / 256, 256, 0, stream>>>(startv, bsum);
    k_scatter<<<gE, 256, 0, stream>>>(ei, startv, cursor, eperm, srcperm);

    // ===== layer 1 =====
    compute_ve<<<1, 32, 0, stream>>>(We1, att_edge1, ve);
    edge_prep<<<gE, 256, 0, stream>>>(eperm, eattr, ve, aeP);
    node_proj_att<false><<<gProj, 256, 0, stream>>>(x, W1, att_src1, att_dst1, A, asrc, adst,
                                                    IN_DIM, (long long)NN * IN_DIM - 1,
                                                    (long long)IN_DIM * HID - 1);
    gat_gather<<<gGat, 256, 0, stream>>>(startv, deg, srcperm, aeP, asrc, adst,
                                         A, b1, B);  // B = h1

    // ===== layer 2 =====
    compute_ve<<<1, 32, 0, stream>>>(We2, att_edge2, ve);
    edge_prep<<<gE, 256, 0, stream>>>(eperm, eattr, ve, aeP);
    node_proj_att<true><<<gProj, 256, 0, stream>>>(B, W2, att_src2, att_dst2, A, asrc, adst,
                                                   HID, (long long)NN * HID - 1,
                                                   (long long)HID * HID - 1);
    gat_gather<<<gGat, 256, 0, stream>>>(startv, deg, srcperm, aeP, asrc, adst,
                                         A, b2, B);  // B = h2

    // ===== pool + classify =====
    hipMemsetAsync(pooled, 0, (64 * HID + 64) * sizeof(float), stream);
    pool_kernel<<<(NN + POOL_CHUNK - 1) / POOL_CHUNK, 256, 0, stream>>>(B, batch, pooled, counts);
    classifier<<<64, 64, 0, stream>>>(pooled, counts, Wc1, bc1, Wc2, bc2, out);
}

// Round 14
// 758.834 us; speedup vs baseline: 1.0718x; 1.0551x over previous
//
#include <hip/hip_runtime.h>

#define NN 100000
#define NE 1600000
#define HID 128
#define HEADS 4
#define CH 32
#define IN_DIM 257
#define CHK 64   // edges per LDS chunk in gather
#define NTP 128  // nodes per projection block
#define KC 16    // K-chunk in projection
#define XST 133  // xt row stride: 133 mod 32 = 5 (coprime) -> conflict-free transposed writes

// ==================== fused node projection + attention scalars ====================
// xt transposed [k][node] (stride 133), staged via COALESCED per-lane global loads +
// transposed ds_write_b32. wt [k][col] staged via global_load_lds width-16.
// 256 threads = 16 mg (8 nodes) x 16 cg (cols {cg*4, 64+cg*4}).
// KC=16 -> 33.4KB LDS -> 4 blocks/CU (all 782 blocks co-resident).
template <bool VEC4>
__global__ __launch_bounds__(256, 4) void node_proj_att(const float* __restrict__ X,
                                                        const float* __restrict__ W,
                                                        const float* __restrict__ att_src,
                                                        const float* __restrict__ att_dst,
                                                        float* __restrict__ XS,
                                                        float* __restrict__ asrc,
                                                        float* __restrict__ adst,
                                                        int K, long long maxx, long long maxw) {
    __shared__ float xt[2][KC][XST];  // transposed: [k][node]
    __shared__ float wt[2][KC][HID];
    int tid = threadIdx.x;
    int lane = tid & 63;
    int wv = tid >> 6;  // wave 0..3
    int block0 = blockIdx.x * NTP;
    int cg = tid & 15;
    int c0a = cg * 4, c0b = 64 + cg * 4;
    int mg = tid >> 4;  // 0..15
    int mbase = mg * 8;
    int nchunk = (K + KC - 1) / KC;

    float4 aA[8], aB[8];
#pragma unroll
    for (int m = 0; m < 8; ++m) {
        aA[m] = make_float4(0.f, 0.f, 0.f, 0.f);
        aB[m] = make_float4(0.f, 0.f, 0.f, 0.f);
    }

    float xreg[8];

    // coalesced global load of next X chunk (128 rows x 16 cols) into registers
    auto loadX = [&](int k0) {
        if (VEC4) {
#pragma unroll
            for (int i = 0; i < 2; ++i) {
                int row = wv * 32 + i * 16 + (lane >> 2);
                int k = (lane & 3) * 4;
                long long src = (long long)(block0 + row) * K + k0 + k;
                if (src > maxx - 3) src = maxx - 3;
                float4 v = *(const float4*)&X[src];
                xreg[i * 4 + 0] = v.x; xreg[i * 4 + 1] = v.y;
                xreg[i * 4 + 2] = v.z; xreg[i * 4 + 3] = v.w;
            }
        } else {
#pragma unroll
            for (int i = 0; i < 8; ++i) {
                int row = wv * 32 + i * 4 + (lane >> 4);
                long long src = (long long)(block0 + row) * K + k0 + (lane & 15);
                if (src > maxx) src = maxx;
                xreg[i] = X[src];
            }
        }
    };
    // transposed LDS write of the register-staged chunk
    auto writeX = [&](int buf) {
        if (VEC4) {
#pragma unroll
            for (int i = 0; i < 2; ++i) {
                int row = wv * 32 + i * 16 + (lane >> 2);
                int k = (lane & 3) * 4;
#pragma unroll
                for (int j = 0; j < 4; ++j) xt[buf][k + j][row] = xreg[i * 4 + j];
            }
        } else {
#pragma unroll
            for (int i = 0; i < 8; ++i) {
                int row = wv * 32 + i * 4 + (lane >> 4);
                xt[buf][lane & 15][row] = xreg[i];
            }
        }
    };
    auto stageW = [&](int buf, int k0) {
#pragma unroll
        for (int i = 0; i < 2; ++i) {
            int idx = wv * 2 + i;  // 0..7, each instr covers 2 k-rows (1024B linear)
            long long src = (long long)(k0 + idx * 2) * HID + lane * 4;
            if (src > maxw - 3) src = maxw - 3;
            __builtin_amdgcn_global_load_lds(
                (const __attribute__((address_space(1))) void*)(W + src),
                (__attribute__((address_space(3))) void*)&wt[buf][idx * 2][0], 16, 0, 0);
        }
    };

    // prologue
    loadX(0);
    stageW(0, 0);
    asm volatile("s_waitcnt vmcnt(0)" ::: "memory");
    writeX(0);
    __syncthreads();

#define ROW8(m, xs)                                                              \
    aA[m].x += (xs)*w0.x; aA[m].y += (xs)*w0.y; aA[m].z += (xs)*w0.z; aA[m].w += (xs)*w0.w; \
    aB[m].x += (xs)*w1.x; aB[m].y += (xs)*w1.y; aB[m].z += (xs)*w1.z; aB[m].w += (xs)*w1.w;

    for (int c = 0; c < nchunk; ++c) {
        int k0 = c * KC;
        int cur = c & 1;
        bool more = (c + 1 < nchunk);
        if (more) { loadX(k0 + KC); stageW(cur ^ 1, k0 + KC); }
        int kc = min(KC, K - k0);
#pragma unroll 1
        for (int kk = 0; kk < kc; ++kk) {
            float4 x0 = *(const float4*)&xt[cur][kk][mbase];
            float4 x1 = *(const float4*)&xt[cur][kk][mbase + 4];
            float4 w0 = *(const float4*)&wt[cur][kk][c0a];
            float4 w1 = *(const float4*)&wt[cur][kk][c0b];
            ROW8(0, x0.x) ROW8(1, x0.y) ROW8(2, x0.z) ROW8(3, x0.w)
            ROW8(4, x1.x) ROW8(5, x1.y) ROW8(6, x1.z) ROW8(7, x1.w)
        }
        if (more) {
            asm volatile("s_waitcnt vmcnt(0)" ::: "memory");
            writeX(cur ^ 1);
        }
        __syncthreads();
    }
#undef ROW8

    // epilogue: write XS + fused per-head attention dots.
    float4 ava = *(const float4*)&att_src[c0a];
    float4 avb = *(const float4*)&att_src[c0b];
    float4 bva = *(const float4*)&att_dst[c0a];
    float4 bvb = *(const float4*)&att_dst[c0b];
    int hA = cg >> 3, hB = 2 + (cg >> 3);
#pragma unroll
    for (int m = 0; m < 8; ++m) {
        int node = block0 + mbase + m;
        float sA = aA[m].x * ava.x + aA[m].y * ava.y + aA[m].z * ava.z + aA[m].w * ava.w;
        float sB = aB[m].x * avb.x + aB[m].y * avb.y + aB[m].z * avb.z + aB[m].w * avb.w;
        float dA = aA[m].x * bva.x + aA[m].y * bva.y + aA[m].z * bva.z + aA[m].w * bva.w;
        float dB = aB[m].x * bvb.x + aB[m].y * bvb.y + aB[m].z * bvb.z + aB[m].w * bvb.w;
        sA += __shfl_xor(sA, 1); sB += __shfl_xor(sB, 1);
        dA += __shfl_xor(dA, 1); dB += __shfl_xor(dB, 1);
        sA += __shfl_xor(sA, 2); sB += __shfl_xor(sB, 2);
        dA += __shfl_xor(dA, 2); dB += __shfl_xor(dB, 2);
        sA += __shfl_xor(sA, 4); sB += __shfl_xor(sB, 4);
        dA += __shfl_xor(dA, 4); dB += __shfl_xor(dB, 4);
        if (node < NN) {
            *(float4*)&XS[(size_t)node * HID + c0a] = aA[m];
            *(float4*)&XS[(size_t)node * HID + c0b] = aB[m];
            if ((cg & 7) == 0) {
                asrc[node * 4 + hA] = sA;
                asrc[node * 4 + hB] = sB;
                adst[node * 4 + hA] = dA;
                adst[node * 4 + hB] = dB;
            }
        }
    }
}

// ---- ve[d,h] = sum_c We[d, h*CH+c] * att_edge[h,c]  (8x4), both layers at once ----
__global__ void compute_ve2(const float* __restrict__ We1,
                            const float* __restrict__ ae1,
                            const float* __restrict__ We2,
                            const float* __restrict__ ae2,
                            float* __restrict__ ve1,
                            float* __restrict__ ve2) {
    int i = threadIdx.x;
    if (i >= 64) return;
    const float* We = (i < 32) ? We1 : We2;
    const float* ae = (i < 32) ? ae1 : ae2;
    float* ve = (i < 32) ? ve1 : ve2;
    int j = i & 31;
    int d = j >> 2, h = j & 3;
    float s = 0.f;
    for (int c = 0; c < CH; ++c) s += We[d * HID + h * CH + c] * ae[h * CH + c];
    ve[j] = s;
}

// ==================== CSR build ====================
__global__ __launch_bounds__(256) void k_deg(const int* __restrict__ ei, int* __restrict__ deg) {
    int e = blockIdx.x * 256 + threadIdx.x;
    if (e < NE) atomicAdd(&deg[ei[NE + e]], 1);
}

__global__ __launch_bounds__(256) void scan_local(const int* __restrict__ deg,
                                                  int* __restrict__ startv,
                                                  int* __restrict__ bsum) {
    __shared__ int sh[256];
    int t = threadIdx.x;
    int base = blockIdx.x * 1024 + t * 4;
    int v0 = 0, v1 = 0, v2 = 0, v3 = 0;
    if (base + 0 < NN) v0 = deg[base + 0];
    if (base + 1 < NN) v1 = deg[base + 1];
    if (base + 2 < NN) v2 = deg[base + 2];
    if (base + 3 < NN) v3 = deg[base + 3];
    int s1 = v0 + v1, s2 = s1 + v2, s3 = s2 + v3;
    sh[t] = s3;
    __syncthreads();
    for (int off = 1; off < 256; off <<= 1) {
        int x = (t >= off) ? sh[t - off] : 0;
        __syncthreads();
        sh[t] += x;
        __syncthreads();
    }
    int thOff = sh[t] - s3;  // exclusive
    if (base + 0 < NN) startv[base + 0] = thOff;
    if (base + 1 < NN) startv[base + 1] = thOff + v0;
    if (base + 2 < NN) startv[base + 2] = thOff + s1;
    if (base + 3 < NN) startv[base + 3] = thOff + s2;
    if (t == 255) bsum[blockIdx.x] = sh[255];
}

__global__ __launch_bounds__(256) void scan_bsum(int* __restrict__ bsum, int nb) {
    __shared__ int sh[256];
    int t = threadIdx.x;
    int v = (t < nb) ? bsum[t] : 0;
    sh[t] = v;
    __syncthreads();
    for (int off = 1; off < 256; off <<= 1) {
        int x = (t >= off) ? sh[t - off] : 0;
        __syncthreads();
        sh[t] += x;
        __syncthreads();
    }
    if (t < nb) bsum[t] = sh[t] - v;  // exclusive
}

__global__ __launch_bounds__(256) void scan_add(int* __restrict__ startv,
                                                const int* __restrict__ bsum) {
    int i = blockIdx.x * 256 + threadIdx.x;
    if (i < NN) startv[i] += bsum[i >> 10];
}

// scatter: permute src index AND the 32B eattr payload (coalesced read, random 32B write).
// Paid once per launch; removes the per-layer random eattr gather entirely.
__global__ __launch_bounds__(256) void k_scatter(const int* __restrict__ ei,
                                                 const int* __restrict__ startv,
                                                 int* __restrict__ cursor,
                                                 const float* __restrict__ eattr,
                                                 int* __restrict__ srcperm,
                                                 float* __restrict__ eattrP) {
    int e = blockIdx.x * 256 + threadIdx.x;
    if (e >= NE) return;
    int d = ei[NE + e];
    float4 e0 = *(const float4*)&eattr[(size_t)e * 8];
    float4 e1 = *(const float4*)&eattr[(size_t)e * 8 + 4];
    int pos = startv[d] + atomicAdd(&cursor[d], 1);
    srcperm[pos] = ei[e];
    *(float4*)&eattrP[(size_t)pos * 8] = e0;
    *(float4*)&eattrP[(size_t)pos * 8 + 4] = e1;
}

// ==================== fused gather: alpha + softmax (no-max) + aggregate + bias + relu ====
// one wave per dst node. Stage reads srcperm (contig 4B) + eattrP (contig 32B) +
// asrc[s] (16B gather, 1.6MB = L2-resident); ae computed inline with ves in LDS.
// Sweep keeps 8 XS row-gathers (contiguous 512B each) in flight.
__global__ __launch_bounds__(256) void gat_gather(const int* __restrict__ startv,
                                                  const int* __restrict__ deg,
                                                  const int* __restrict__ srcperm,
                                                  const float* __restrict__ eattrP,
                                                  const float* __restrict__ ve,
                                                  const float* __restrict__ asrc,
                                                  const float* __restrict__ adst,
                                                  const float* __restrict__ XS,
                                                  const float* __restrict__ bias,
                                                  float* __restrict__ OUT) {
    __shared__ float s_p[4][CHK * 4];
    __shared__ int s_src[4][CHK];
    __shared__ float ves[32];
    if (threadIdx.x < 32) ves[threadIdx.x] = ve[threadIdx.x];
    __syncthreads();
    int w = threadIdx.x >> 6;
    int wid = blockIdx.x * 4 + w;
    if (wid >= NN) return;
    int lane = threadIdx.x & 63;
    int s0 = startv[wid];
    int dg = deg[wid];
    float4 ad4 = *(const float4*)&adst[wid * 4];
    float adh[4] = {ad4.x, ad4.y, ad4.z, ad4.w};
    int h = lane >> 4;
    int c0 = lane * 2;

    float denom = 0.f, acc0 = 0.f, acc1 = 0.f;

    for (int cb = 0; cb < dg; cb += CHK) {
        int cnt = min(CHK, dg - cb);
        // stage: src index + per-head p = exp(alpha) into LDS (wave-synchronous)
        for (int i = lane; i < cnt; i += 64) {
            int pos = s0 + cb + i;
            int s = srcperm[pos];
            s_src[w][i] = s;
            float4 e0 = *(const float4*)&eattrP[(size_t)pos * 8];
            float4 e1 = *(const float4*)&eattrP[(size_t)pos * 8 + 4];
            float eav[8] = {e0.x, e0.y, e0.z, e0.w, e1.x, e1.y, e1.z, e1.w};
            float4 as4 = *(const float4*)&asrc[s * 4];
            float ash[4] = {as4.x, as4.y, as4.z, as4.w};
            float p[4];
#pragma unroll
            for (int hh = 0; hh < 4; ++hh) {
                float ae = 0.f;
#pragma unroll
                for (int dd = 0; dd < 8; ++dd) ae += eav[dd] * ves[dd * 4 + hh];
                float a = ash[hh] + adh[hh] + ae;
                a = (a > 0.f) ? a : 0.2f * a;
                p[hh] = __expf(a);
            }
            *(float4*)&s_p[w][i * 4] = make_float4(p[0], p[1], p[2], p[3]);
        }
        // accumulate sweep, 8 XS gathers in flight
        int j = 0;
        for (; j + 7 < cnt; j += 8) {
            int sv[8];
            float pv[8];
            float2 xv[8];
#pragma unroll
            for (int q = 0; q < 8; ++q) {
                sv[q] = s_src[w][j + q];
                pv[q] = s_p[w][(j + q) * 4 + h];
            }
#pragma unroll
            for (int q = 0; q < 8; ++q) xv[q] = *(const float2*)&XS[(size_t)sv[q] * HID + c0];
#pragma unroll
            for (int q = 0; q < 8; ++q) {
                denom += pv[q];
                acc0 += pv[q] * xv[q].x;
                acc1 += pv[q] * xv[q].y;
            }
        }
        for (; j + 3 < cnt; j += 4) {
            int sA = s_src[w][j], sB = s_src[w][j + 1], sC = s_src[w][j + 2], sD = s_src[w][j + 3];
            float pA = s_p[w][j * 4 + h], pB = s_p[w][(j + 1) * 4 + h];
            float pC = s_p[w][(j + 2) * 4 + h], pD = s_p[w][(j + 3) * 4 + h];
            float2 xA = *(const float2*)&XS[(size_t)sA * HID + c0];
            float2 xB = *(const float2*)&XS[(size_t)sB * HID + c0];
            float2 xC = *(const float2*)&XS[(size_t)sC * HID + c0];
            float2 xD = *(const float2*)&XS[(size_t)sD * HID + c0];
            denom += pA + pB + pC + pD;
            acc0 += pA * xA.x + pB * xB.x + pC * xC.x + pD * xD.x;
            acc1 += pA * xA.y + pB * xB.y + pC * xC.y + pD * xD.y;
        }
        for (; j < cnt; ++j) {
            int s = s_src[w][j];
            float p = s_p[w][j * 4 + h];
            float2 xv = *(const float2*)&XS[(size_t)s * HID + c0];
            denom += p;
            acc0 += p * xv.x;
            acc1 += p * xv.y;
        }
    }
    float inv = 1.f / (denom + 1e-16f);
    float2 bv = *(const float2*)&bias[c0];
    float o0 = fmaxf(acc0 * inv + bv.x, 0.f);
    float o1 = fmaxf(acc1 * inv + bv.y, 0.f);
    *(float2*)&OUT[(size_t)wid * HID + c0] = make_float2(o0, o1);
}

// ==================== pooling ====================
#define POOL_CHUNK 512
__global__ __launch_bounds__(256) void pool_kernel(const float* __restrict__ H,
                                                   const int* __restrict__ batch,
                                                   float* __restrict__ pooled,
                                                   float* __restrict__ counts) {
    __shared__ float tab[64 * HID];
    __shared__ float cnt[64];
    int tid = threadIdx.x;
    int n0 = blockIdx.x * POOL_CHUNK;
    int nmax = min(POOL_CHUNK, NN - n0);
    for (int i = tid; i < 64 * HID; i += 256) tab[i] = 0.f;
    if (tid < 64) cnt[tid] = 0.f;
    __syncthreads();
    for (int i = tid; i < nmax * HID; i += 256) {
        int n = n0 + (i >> 7), c = i & 127;
        int g = batch[n];
        atomicAdd(&tab[g * HID + c], H[(long long)n * HID + c]);
    }
    for (int n = tid; n < nmax; n += 256) atomicAdd(&cnt[batch[n0 + n]], 1.f);
    __syncthreads();
    int gmin = batch[n0], gmax = batch[n0 + nmax - 1];
    int ng = gmax - gmin + 1;
    for (int i = tid; i < ng * HID; i += 256) {
        int g = gmin + (i >> 7), c = i & 127;
        atomicAdd(&pooled[g * HID + c], tab[g * HID + c]);
    }
    if (tid < ng) atomicAdd(&counts[gmin + tid], cnt[gmin + tid]);
}

// ==================== classifier ====================
__global__ __launch_bounds__(64) void classifier(const float* __restrict__ pooled,
                                                 const float* __restrict__ counts,
                                                 const float* __restrict__ Wc1,
                                                 const float* __restrict__ bc1,
                                                 const float* __restrict__ Wc2,
                                                 const float* __restrict__ bc2,
                                                 float* __restrict__ out) {
    __shared__ float pl[HID];
    __shared__ float z[64];
    int g = blockIdx.x, t = threadIdx.x;
    float inv = 1.f / fmaxf(counts[g], 1.f);
    pl[t] = pooled[g * HID + t] * inv;
    pl[t + 64] = pooled[g * HID + 64 + t] * inv;
    __syncthreads();
    float a = bc1[t];
    for (int k = 0; k < HID; ++k) a += pl[k] * Wc1[k * 64 + t];
    z[t] = fmaxf(a, 0.f);
    __syncthreads();
    if (t < 2) {
        float o = bc2[t];
        for (int j = 0; j < 64; ++j) o += z[j] * Wc2[j * 2 + t];
        out[g * 2 + t] = o;
    }
}

extern "C" void kernel_launch(void* const* d_in, const int* in_sizes, int n_in,
                              void* d_out, int out_size, void* d_ws, size_t ws_size,
                              hipStream_t stream) {
    const float* x = (const float*)d_in[0];
    const int* ei = (const int*)d_in[1];
    const float* eattr = (const float*)d_in[2];
    const int* batch = (const int*)d_in[3];
    const float* W1 = (const float*)d_in[4];
    const float* att_src1 = (const float*)d_in[5];
    const float* att_dst1 = (const float*)d_in[6];
    const float* We1 = (const float*)d_in[7];
    const float* att_edge1 = (const float*)d_in[8];
    const float* b1 = (const float*)d_in[9];
    const float* W2 = (const float*)d_in[10];
    const float* att_src2 = (const float*)d_in[11];
    const float* att_dst2 = (const float*)d_in[12];
    const float* We2 = (const float*)d_in[13];
    const float* att_edge2 = (const float*)d_in[14];
    const float* b2 = (const float*)d_in[15];
    const float* Wc1 = (const float*)d_in[16];
    const float* bc1 = (const float*)d_in[17];
    const float* Wc2 = (const float*)d_in[18];
    const float* bc2 = (const float*)d_in[19];
    float* out = (float*)d_out;

    // workspace layout (floats then ints; deg+cursor adjacent for one memset)
    float* A = (float*)d_ws;                        // xs buffer [N,128]
    float* B = A + (size_t)NN * HID;                // h buffer [N,128]
    float* asrc = B + (size_t)NN * HID;             // [N,4]
    float* adst = asrc + (size_t)NN * 4;            // [N,4]
    float* ve1 = adst + (size_t)NN * 4;             // [32]
    float* ve2 = ve1 + 32;                          // [32]
    float* pooled = ve2 + 32;                       // [64,128]
    float* counts = pooled + 64 * HID;              // [64]
    float* eattrP = counts + 64;                    // [E,8] permuted edge attrs
    int* deg = (int*)(eattrP + (size_t)NE * 8);     // [N]
    int* cursor = deg + NN;                         // [N]
    int* startv = cursor + NN;                      // [N]
    int* bsum = startv + NN;                        // [256]
    int* srcperm = bsum + 256;                      // [E]

    int gProj = (NN + NTP - 1) / NTP;  // 782
    int gE = (NE + 255) / 256;
    int gGat = (NN + 3) / 4;
    int nScanBlk = (NN + 1023) / 1024;  // 98

    // ===== CSR build + edge permutation (once per launch) =====
    hipMemsetAsync(deg, 0, (size_t)2 * NN * sizeof(int), stream);  // deg + cursor
    k_deg<<<gE, 256, 0, stream>>>(ei, deg);
    scan_local<<<nScanBlk, 256, 0, stream>>>(deg, startv, bsum);
    scan_bsum<<<1, 256, 0, stream>>>(bsum, nScanBlk);
    scan_add<<<(NN + 255) / 256, 256, 0, stream>>>(startv, bsum);
    k_scatter<<<gE, 256, 0, stream>>>(ei, startv, cursor, eattr, srcperm, eattrP);
    compute_ve2<<<1, 64, 0, stream>>>(We1, att_edge1, We2, att_edge2, ve1, ve2);

    // ===== layer 1 =====
    node_proj_att<false><<<gProj, 256, 0, stream>>>(x, W1, att_src1, att_dst1, A, asrc, adst,
                                                    IN_DIM, (long long)NN * IN_DIM - 1,
                                                    (long long)IN_DIM * HID - 1);
    gat_gather<<<gGat, 256, 0, stream>>>(startv, deg, srcperm, eattrP, ve1, asrc, adst,
                                         A, b1, B);  // B = h1

    // ===== layer 2 =====
    node_proj_att<true><<<gProj, 256, 0, stream>>>(B, W2, att_src2, att_dst2, A, asrc, adst,
                                                   HID, (long long)NN * HID - 1,
                                                   (long long)HID * HID - 1);
    gat_gather<<<gGat, 256, 0, stream>>>(startv, deg, srcperm, eattrP, ve2, asrc, adst,
                                         A, b2, B);  // B = h2

    // ===== pool + classify =====
    hipMemsetAsync(pooled, 0, (64 * HID + 64) * sizeof(float), stream);
    pool_kernel<<<(NN + POOL_CHUNK - 1) / POOL_CHUNK, 256, 0, stream>>>(B, batch, pooled, counts);
    classifier<<<64, 64, 0, stream>>>(pooled, counts, Wc1, bc1, Wc2, bc2, out);
}

// Round 15
// 738.860 us; speedup vs baseline: 1.1007x; 1.0270x over previous
//
#include <hip/hip_runtime.h>

#define NN 100000
#define NE 1600000
#define HID 128
#define HEADS 4
#define CH 32
#define IN_DIM 257
#define CHK 64   // edges per LDS chunk in gather
#define NTP 128  // nodes per projection block
#define KC 16    // K-chunk in projection
#define XST 133  // xt row stride: 133 mod 32 = 5 (coprime) -> conflict-free transposed writes

typedef float f4v __attribute__((ext_vector_type(4)));
typedef float f2v __attribute__((ext_vector_type(2)));

__device__ __forceinline__ float4 ntload4(const float* p) {
    f4v v = __builtin_nontemporal_load((const f4v*)p);
    return make_float4(v.x, v.y, v.z, v.w);
}
__device__ __forceinline__ void ntstore2(float* p, float a, float b) {
    f2v v = {a, b};
    __builtin_nontemporal_store(v, (f2v*)p);
}

// ==================== fused node projection + attention scalars ====================
// xt transposed [k][node] (stride 133), staged via COALESCED per-lane global loads +
// transposed ds_write_b32. wt [k][col] staged via global_load_lds width-16.
// 256 threads = 16 mg (8 nodes) x 16 cg (cols {cg*4, 64+cg*4}).
template <bool VEC4>
__global__ __launch_bounds__(256, 4) void node_proj_att(const float* __restrict__ X,
                                                        const float* __restrict__ W,
                                                        const float* __restrict__ att_src,
                                                        const float* __restrict__ att_dst,
                                                        float* __restrict__ XS,
                                                        float* __restrict__ asrc,
                                                        float* __restrict__ adst,
                                                        int K, long long maxx, long long maxw) {
    __shared__ float xt[2][KC][XST];  // transposed: [k][node]
    __shared__ float wt[2][KC][HID];
    int tid = threadIdx.x;
    int lane = tid & 63;
    int wv = tid >> 6;  // wave 0..3
    int block0 = blockIdx.x * NTP;
    int cg = tid & 15;
    int c0a = cg * 4, c0b = 64 + cg * 4;
    int mg = tid >> 4;  // 0..15
    int mbase = mg * 8;
    int nchunk = (K + KC - 1) / KC;

    float4 aA[8], aB[8];
#pragma unroll
    for (int m = 0; m < 8; ++m) {
        aA[m] = make_float4(0.f, 0.f, 0.f, 0.f);
        aB[m] = make_float4(0.f, 0.f, 0.f, 0.f);
    }

    float xreg[8];

    auto loadX = [&](int k0) {
        if (VEC4) {
#pragma unroll
            for (int i = 0; i < 2; ++i) {
                int row = wv * 32 + i * 16 + (lane >> 2);
                int k = (lane & 3) * 4;
                long long src = (long long)(block0 + row) * K + k0 + k;
                if (src > maxx - 3) src = maxx - 3;
                float4 v = *(const float4*)&X[src];
                xreg[i * 4 + 0] = v.x; xreg[i * 4 + 1] = v.y;
                xreg[i * 4 + 2] = v.z; xreg[i * 4 + 3] = v.w;
            }
        } else {
#pragma unroll
            for (int i = 0; i < 8; ++i) {
                int row = wv * 32 + i * 4 + (lane >> 4);
                long long src = (long long)(block0 + row) * K + k0 + (lane & 15);
                if (src > maxx) src = maxx;
                xreg[i] = X[src];
            }
        }
    };
    auto writeX = [&](int buf) {
        if (VEC4) {
#pragma unroll
            for (int i = 0; i < 2; ++i) {
                int row = wv * 32 + i * 16 + (lane >> 2);
                int k = (lane & 3) * 4;
#pragma unroll
                for (int j = 0; j < 4; ++j) xt[buf][k + j][row] = xreg[i * 4 + j];
            }
        } else {
#pragma unroll
            for (int i = 0; i < 8; ++i) {
                int row = wv * 32 + i * 4 + (lane >> 4);
                xt[buf][lane & 15][row] = xreg[i];
            }
        }
    };
    auto stageW = [&](int buf, int k0) {
#pragma unroll
        for (int i = 0; i < 2; ++i) {
            int idx = wv * 2 + i;  // 0..7, each instr covers 2 k-rows (1024B linear)
            long long src = (long long)(k0 + idx * 2) * HID + lane * 4;
            if (src > maxw - 3) src = maxw - 3;
            __builtin_amdgcn_global_load_lds(
                (const __attribute__((address_space(1))) void*)(W + src),
                (__attribute__((address_space(3))) void*)&wt[buf][idx * 2][0], 16, 0, 0);
        }
    };

    // prologue
    loadX(0);
    stageW(0, 0);
    asm volatile("s_waitcnt vmcnt(0)" ::: "memory");
    writeX(0);
    __syncthreads();

#define ROW8(m, xs)                                                              \
    aA[m].x += (xs)*w0.x; aA[m].y += (xs)*w0.y; aA[m].z += (xs)*w0.z; aA[m].w += (xs)*w0.w; \
    aB[m].x += (xs)*w1.x; aB[m].y += (xs)*w1.y; aB[m].z += (xs)*w1.z; aB[m].w += (xs)*w1.w;

    for (int c = 0; c < nchunk; ++c) {
        int k0 = c * KC;
        int cur = c & 1;
        bool more = (c + 1 < nchunk);
        if (more) { loadX(k0 + KC); stageW(cur ^ 1, k0 + KC); }
        int kc = min(KC, K - k0);
#pragma unroll 1
        for (int kk = 0; kk < kc; ++kk) {
            float4 x0 = *(const float4*)&xt[cur][kk][mbase];
            float4 x1 = *(const float4*)&xt[cur][kk][mbase + 4];
            float4 w0 = *(const float4*)&wt[cur][kk][c0a];
            float4 w1 = *(const float4*)&wt[cur][kk][c0b];
            ROW8(0, x0.x) ROW8(1, x0.y) ROW8(2, x0.z) ROW8(3, x0.w)
            ROW8(4, x1.x) ROW8(5, x1.y) ROW8(6, x1.z) ROW8(7, x1.w)
        }
        if (more) {
            asm volatile("s_waitcnt vmcnt(0)" ::: "memory");
            writeX(cur ^ 1);
        }
        __syncthreads();
    }
#undef ROW8

    // epilogue: write XS + fused per-head attention dots.
    float4 ava = *(const float4*)&att_src[c0a];
    float4 avb = *(const float4*)&att_src[c0b];
    float4 bva = *(const float4*)&att_dst[c0a];
    float4 bvb = *(const float4*)&att_dst[c0b];
    int hA = cg >> 3, hB = 2 + (cg >> 3);
#pragma unroll
    for (int m = 0; m < 8; ++m) {
        int node = block0 + mbase + m;
        float sA = aA[m].x * ava.x + aA[m].y * ava.y + aA[m].z * ava.z + aA[m].w * ava.w;
        float sB = aB[m].x * avb.x + aB[m].y * avb.y + aB[m].z * avb.z + aB[m].w * avb.w;
        float dA = aA[m].x * bva.x + aA[m].y * bva.y + aA[m].z * bva.z + aA[m].w * bva.w;
        float dB = aB[m].x * bvb.x + aB[m].y * bvb.y + aB[m].z * bvb.z + aB[m].w * bvb.w;
        sA += __shfl_xor(sA, 1); sB += __shfl_xor(sB, 1);
        dA += __shfl_xor(dA, 1); dB += __shfl_xor(dB, 1);
        sA += __shfl_xor(sA, 2); sB += __shfl_xor(sB, 2);
        dA += __shfl_xor(dA, 2); dB += __shfl_xor(dB, 2);
        sA += __shfl_xor(sA, 4); sB += __shfl_xor(sB, 4);
        dA += __shfl_xor(dA, 4); dB += __shfl_xor(dB, 4);
        if (node < NN) {
            *(float4*)&XS[(size_t)node * HID + c0a] = aA[m];
            *(float4*)&XS[(size_t)node * HID + c0b] = aB[m];
            if ((cg & 7) == 0) {
                asrc[node * 4 + hA] = sA;
                asrc[node * 4 + hB] = sB;
                adst[node * 4 + hA] = dA;
                adst[node * 4 + hB] = dB;
            }
        }
    }
}

// ---- ve[d,h] = sum_c We[d, h*CH+c] * att_edge[h,c]  (8x4), both layers at once ----
__global__ void compute_ve2(const float* __restrict__ We1,
                            const float* __restrict__ ae1,
                            const float* __restrict__ We2,
                            const float* __restrict__ ae2,
                            float* __restrict__ ve1,
                            float* __restrict__ ve2) {
    int i = threadIdx.x;
    if (i >= 64) return;
    const float* We = (i < 32) ? We1 : We2;
    const float* ae = (i < 32) ? ae1 : ae2;
    float* ve = (i < 32) ? ve1 : ve2;
    int j = i & 31;
    int d = j >> 2, h = j & 3;
    float s = 0.f;
    for (int c = 0; c < CH; ++c) s += We[d * HID + h * CH + c] * ae[h * CH + c];
    ve[j] = s;
}

// ==================== CSR build ====================
__global__ __launch_bounds__(256) void k_deg(const int* __restrict__ ei, int* __restrict__ deg) {
    int e = blockIdx.x * 256 + threadIdx.x;
    if (e < NE) atomicAdd(&deg[ei[NE + e]], 1);
}

__global__ __launch_bounds__(256) void scan_local(const int* __restrict__ deg,
                                                  int* __restrict__ startv,
                                                  int* __restrict__ bsum) {
    __shared__ int sh[256];
    int t = threadIdx.x;
    int base = blockIdx.x * 1024 + t * 4;
    int v0 = 0, v1 = 0, v2 = 0, v3 = 0;
    if (base + 0 < NN) v0 = deg[base + 0];
    if (base + 1 < NN) v1 = deg[base + 1];
    if (base + 2 < NN) v2 = deg[base + 2];
    if (base + 3 < NN) v3 = deg[base + 3];
    int s1 = v0 + v1, s2 = s1 + v2, s3 = s2 + v3;
    sh[t] = s3;
    __syncthreads();
    for (int off = 1; off < 256; off <<= 1) {
        int x = (t >= off) ? sh[t - off] : 0;
        __syncthreads();
        sh[t] += x;
        __syncthreads();
    }
    int thOff = sh[t] - s3;  // exclusive
    if (base + 0 < NN) startv[base + 0] = thOff;
    if (base + 1 < NN) startv[base + 1] = thOff + v0;
    if (base + 2 < NN) startv[base + 2] = thOff + s1;
    if (base + 3 < NN) startv[base + 3] = thOff + s2;
    if (t == 255) bsum[blockIdx.x] = sh[255];
}

__global__ __launch_bounds__(256) void scan_bsum(int* __restrict__ bsum, int nb) {
    __shared__ int sh[256];
    int t = threadIdx.x;
    int v = (t < nb) ? bsum[t] : 0;
    sh[t] = v;
    __syncthreads();
    for (int off = 1; off < 256; off <<= 1) {
        int x = (t >= off) ? sh[t - off] : 0;
        __syncthreads();
        sh[t] += x;
        __syncthreads();
    }
    if (t < nb) bsum[t] = sh[t] - v;  // exclusive
}

__global__ __launch_bounds__(256) void scan_add(int* __restrict__ startv,
                                                const int* __restrict__ bsum) {
    int i = blockIdx.x * 256 + threadIdx.x;
    if (i < NN) startv[i] += bsum[i >> 10];
}

// scatter: permute src index AND precompute both layers' a_edge dots (32B record).
// Coalesced eattr read; one random 32B write per edge. Paid once per launch.
__global__ __launch_bounds__(256) void k_scatter(const int* __restrict__ ei,
                                                 const int* __restrict__ startv,
                                                 int* __restrict__ cursor,
                                                 const float* __restrict__ eattr,
                                                 const float* __restrict__ ve1,
                                                 const float* __restrict__ ve2,
                                                 int* __restrict__ srcperm,
                                                 float* __restrict__ aeP12) {
    __shared__ float v1[32], v2[32];
    if (threadIdx.x < 32) v1[threadIdx.x] = ve1[threadIdx.x];
    else if (threadIdx.x < 64) v2[threadIdx.x - 32] = ve2[threadIdx.x - 32];
    __syncthreads();
    int e = blockIdx.x * 256 + threadIdx.x;
    if (e >= NE) return;
    int d = ei[NE + e];
    float4 e0 = *(const float4*)&eattr[(size_t)e * 8];
    float4 e1 = *(const float4*)&eattr[(size_t)e * 8 + 4];
    float eav[8] = {e0.x, e0.y, e0.z, e0.w, e1.x, e1.y, e1.z, e1.w};
    float a1[4], a2[4];
#pragma unroll
    for (int hh = 0; hh < 4; ++hh) {
        float s1 = 0.f, s2 = 0.f;
#pragma unroll
        for (int dd = 0; dd < 8; ++dd) {
            s1 += eav[dd] * v1[dd * 4 + hh];
            s2 += eav[dd] * v2[dd * 4 + hh];
        }
        a1[hh] = s1;
        a2[hh] = s2;
    }
    int pos = startv[d] + atomicAdd(&cursor[d], 1);
    srcperm[pos] = ei[e];
    *(float4*)&aeP12[(size_t)pos * 8] = make_float4(a1[0], a1[1], a1[2], a1[3]);
    *(float4*)&aeP12[(size_t)pos * 8 + 4] = make_float4(a2[0], a2[1], a2[2], a2[3]);
}

// ==================== fused gather: softmax (no-max) + aggregate + bias + relu ====
// one wave per dst node. Stage reads srcperm (nt) + aeP half-record (nt) + asrc[s]
// (cached, L2-resident); p = exp(leaky(as+ad+ae)). Streaming accesses are NON-TEMPORAL
// so L3 retains XS (51MB, ~16x reuse). Sweep keeps 8 XS row-gathers in flight.
__global__ __launch_bounds__(256) void gat_gather(const int* __restrict__ startv,
                                                  const int* __restrict__ deg,
                                                  const int* __restrict__ srcperm,
                                                  const float* __restrict__ aeL,  // aeP12 + layer*4
                                                  const float* __restrict__ asrc,
                                                  const float* __restrict__ adst,
                                                  const float* __restrict__ XS,
                                                  const float* __restrict__ bias,
                                                  float* __restrict__ OUT) {
    __shared__ float s_p[4][CHK * 4];
    __shared__ int s_src[4][CHK];
    int w = threadIdx.x >> 6;
    int wid = blockIdx.x * 4 + w;
    if (wid >= NN) return;
    int lane = threadIdx.x & 63;
    int s0 = startv[wid];
    int dg = deg[wid];
    float4 ad4 = *(const float4*)&adst[wid * 4];
    int h = lane >> 4;
    int c0 = lane * 2;

    float denom = 0.f, acc0 = 0.f, acc1 = 0.f;

    for (int cb = 0; cb < dg; cb += CHK) {
        int cnt = min(CHK, dg - cb);
        // stage: src index + per-head p = exp(alpha) into LDS (wave-synchronous)
        for (int i = lane; i < cnt; i += 64) {
            int pos = s0 + cb + i;
            int s = __builtin_nontemporal_load(&srcperm[pos]);
            s_src[w][i] = s;
            float4 ae = ntload4(&aeL[(size_t)pos * 8]);
            float4 as4 = *(const float4*)&asrc[s * 4];
            float a0 = as4.x + ad4.x + ae.x;
            float a1 = as4.y + ad4.y + ae.y;
            float a2 = as4.z + ad4.z + ae.z;
            float a3 = as4.w + ad4.w + ae.w;
            a0 = (a0 > 0.f) ? a0 : 0.2f * a0;
            a1 = (a1 > 0.f) ? a1 : 0.2f * a1;
            a2 = (a2 > 0.f) ? a2 : 0.2f * a2;
            a3 = (a3 > 0.f) ? a3 : 0.2f * a3;
            *(float4*)&s_p[w][i * 4] =
                make_float4(__expf(a0), __expf(a1), __expf(a2), __expf(a3));
        }
        // accumulate sweep, 8 XS gathers in flight
        int j = 0;
        for (; j + 7 < cnt; j += 8) {
            int sv[8];
            float pv[8];
            float2 xv[8];
#pragma unroll
            for (int q = 0; q < 8; ++q) {
                sv[q] = s_src[w][j + q];
                pv[q] = s_p[w][(j + q) * 4 + h];
            }
#pragma unroll
            for (int q = 0; q < 8; ++q) xv[q] = *(const float2*)&XS[(size_t)sv[q] * HID + c0];
#pragma unroll
            for (int q = 0; q < 8; ++q) {
                denom += pv[q];
                acc0 += pv[q] * xv[q].x;
                acc1 += pv[q] * xv[q].y;
            }
        }
        for (; j + 3 < cnt; j += 4) {
            int sA = s_src[w][j], sB = s_src[w][j + 1], sC = s_src[w][j + 2], sD = s_src[w][j + 3];
            float pA = s_p[w][j * 4 + h], pB = s_p[w][(j + 1) * 4 + h];
            float pC = s_p[w][(j + 2) * 4 + h], pD = s_p[w][(j + 3) * 4 + h];
            float2 xA = *(const float2*)&XS[(size_t)sA * HID + c0];
            float2 xB = *(const float2*)&XS[(size_t)sB * HID + c0];
            float2 xC = *(const float2*)&XS[(size_t)sC * HID + c0];
            float2 xD = *(const float2*)&XS[(size_t)sD * HID + c0];
            denom += pA + pB + pC + pD;
            acc0 += pA * xA.x + pB * xB.x + pC * xC.x + pD * xD.x;
            acc1 += pA * xA.y + pB * xB.y + pC * xC.y + pD * xD.y;
        }
        for (; j < cnt; ++j) {
            int s = s_src[w][j];
            float p = s_p[w][j * 4 + h];
            float2 xv = *(const float2*)&XS[(size_t)s * HID + c0];
            denom += p;
            acc0 += p * xv.x;
            acc1 += p * xv.y;
        }
    }
    float inv = 1.f / (denom + 1e-16f);
    float2 bv = *(const float2*)&bias[c0];
    float o0 = fmaxf(acc0 * inv + bv.x, 0.f);
    float o1 = fmaxf(acc1 * inv + bv.y, 0.f);
    ntstore2(&OUT[(size_t)wid * HID + c0], o0, o1);
}

// ==================== pooling ====================
#define POOL_CHUNK 512
__global__ __launch_bounds__(256) void pool_kernel(const float* __restrict__ H,
                                                   const int* __restrict__ batch,
                                                   float* __restrict__ pooled,
                                                   float* __restrict__ counts) {
    __shared__ float tab[64 * HID];
    __shared__ float cnt[64];
    int tid = threadIdx.x;
    int n0 = blockIdx.x * POOL_CHUNK;
    int nmax = min(POOL_CHUNK, NN - n0);
    for (int i = tid; i < 64 * HID; i += 256) tab[i] = 0.f;
    if (tid < 64) cnt[tid] = 0.f;
    __syncthreads();
    for (int i = tid; i < nmax * HID; i += 256) {
        int n = n0 + (i >> 7), c = i & 127;
        int g = batch[n];
        atomicAdd(&tab[g * HID + c], H[(long long)n * HID + c]);
    }
    for (int n = tid; n < nmax; n += 256) atomicAdd(&cnt[batch[n0 + n]], 1.f);
    __syncthreads();
    int gmin = batch[n0], gmax = batch[n0 + nmax - 1];
    int ng = gmax - gmin + 1;
    for (int i = tid; i < ng * HID; i += 256) {
        int g = gmin + (i >> 7), c = i & 127;
        atomicAdd(&pooled[g * HID + c], tab[g * HID + c]);
    }
    if (tid < ng) atomicAdd(&counts[gmin + tid], cnt[gmin + tid]);
}

// ==================== classifier ====================
__global__ __launch_bounds__(64) void classifier(const float* __restrict__ pooled,
                                                 const float* __restrict__ counts,
                                                 const float* __restrict__ Wc1,
                                                 const float* __restrict__ bc1,
                                                 const float* __restrict__ Wc2,
                                                 const float* __restrict__ bc2,
                                                 float* __restrict__ out) {
    __shared__ float pl[HID];
    __shared__ float z[64];
    int g = blockIdx.x, t = threadIdx.x;
    float inv = 1.f / fmaxf(counts[g], 1.f);
    pl[t] = pooled[g * HID + t] * inv;
    pl[t + 64] = pooled[g * HID + 64 + t] * inv;
    __syncthreads();
    float a = bc1[t];
    for (int k = 0; k < HID; ++k) a += pl[k] * Wc1[k * 64 + t];
    z[t] = fmaxf(a, 0.f);
    __syncthreads();
    if (t < 2) {
        float o = bc2[t];
        for (int j = 0; j < 64; ++j) o += z[j] * Wc2[j * 2 + t];
        out[g * 2 + t] = o;
    }
}

extern "C" void kernel_launch(void* const* d_in, const int* in_sizes, int n_in,
                              void* d_out, int out_size, void* d_ws, size_t ws_size,
                              hipStream_t stream) {
    const float* x = (const float*)d_in[0];
    const int* ei = (const int*)d_in[1];
    const float* eattr = (const float*)d_in[2];
    const int* batch = (const int*)d_in[3];
    const float* W1 = (const float*)d_in[4];
    const float* att_src1 = (const float*)d_in[5];
    const float* att_dst1 = (const float*)d_in[6];
    const float* We1 = (const float*)d_in[7];
    const float* att_edge1 = (const float*)d_in[8];
    const float* b1 = (const float*)d_in[9];
    const float* W2 = (const float*)d_in[10];
    const float* att_src2 = (const float*)d_in[11];
    const float* att_dst2 = (const float*)d_in[12];
    const float* We2 = (const float*)d_in[13];
    const float* att_edge2 = (const float*)d_in[14];
    const float* b2 = (const float*)d_in[15];
    const float* Wc1 = (const float*)d_in[16];
    const float* bc1 = (const float*)d_in[17];
    const float* Wc2 = (const float*)d_in[18];
    const float* bc2 = (const float*)d_in[19];
    float* out = (float*)d_out;

    // workspace layout (floats then ints; deg+cursor adjacent for one memset)
    float* A = (float*)d_ws;                        // xs buffer [N,128]
    float* B = A + (size_t)NN * HID;                // h buffer [N,128]
    float* asrc = B + (size_t)NN * HID;             // [N,4]
    float* adst = asrc + (size_t)NN * 4;            // [N,4]
    float* ve1 = adst + (size_t)NN * 4;             // [32]
    float* ve2 = ve1 + 32;                          // [32]
    float* pooled = ve2 + 32;                       // [64,128]
    float* counts = pooled + 64 * HID;              // [64]
    float* aeP12 = counts + 64;                     // [E,8] permuted {ae1[4], ae2[4]}
    int* deg = (int*)(aeP12 + (size_t)NE * 8);      // [N]
    int* cursor = deg + NN;                         // [N]
    int* startv = cursor + NN;                      // [N]
    int* bsum = startv + NN;                        // [256]
    int* srcperm = bsum + 256;                      // [E]

    int gProj = (NN + NTP - 1) / NTP;  // 782
    int gE = (NE + 255) / 256;
    int gGat = (NN + 3) / 4;
    int nScanBlk = (NN + 1023) / 1024;  // 98

    // ===== CSR build + edge permutation (once per launch) =====
    hipMemsetAsync(deg, 0, (size_t)2 * NN * sizeof(int), stream);  // deg + cursor
    compute_ve2<<<1, 64, 0, stream>>>(We1, att_edge1, We2, att_edge2, ve1, ve2);
    k_deg<<<gE, 256, 0, stream>>>(ei, deg);
    scan_local<<<nScanBlk, 256, 0, stream>>>(deg, startv, bsum);
    scan_bsum<<<1, 256, 0, stream>>>(bsum, nScanBlk);
    scan_add<<<(NN + 255) / 256, 256, 0, stream>>>(startv, bsum);
    k_scatter<<<gE, 256, 0, stream>>>(ei, startv, cursor, eattr, ve1, ve2, srcperm, aeP12);

    // ===== layer 1 =====
    node_proj_att<false><<<gProj, 256, 0, stream>>>(x, W1, att_src1, att_dst1, A, asrc, adst,
                                                    IN_DIM, (long long)NN * IN_DIM - 1,
                                                    (long long)IN_DIM * HID - 1);
    gat_gather<<<gGat, 256, 0, stream>>>(startv, deg, srcperm, aeP12, asrc, adst,
                                         A, b1, B);  // B = h1

    // ===== layer 2 =====
    node_proj_att<true><<<gProj, 256, 0, stream>>>(B, W2, att_src2, att_dst2, A, asrc, adst,
                                                   HID, (long long)NN * HID - 1,
                                                   (long long)HID * HID - 1);
    gat_gather<<<gGat, 256, 0, stream>>>(startv, deg, srcperm, aeP12 + 4, asrc, adst,
                                         A, b2, B);  // B = h2

    // ===== pool + classify =====
    hipMemsetAsync(pooled, 0, (64 * HID + 64) * sizeof(float), stream);
    pool_kernel<<<(NN + POOL_CHUNK - 1) / POOL_CHUNK, 256, 0, stream>>>(B, batch, pooled, counts);
    classifier<<<64, 64, 0, stream>>>(pooled, counts, Wc1, bc1, Wc2, bc2, out);
}

// Round 16
// 634.258 us; speedup vs baseline: 1.2823x; 1.1649x over previous
//
#include <hip/hip_runtime.h>
#include <hip/hip_fp16.h>

#define NN 100000
#define NE 1600000
#define HID 128
#define HEADS 4
#define CH 32
#define IN_DIM 257
#define CHK 64   // edges per LDS chunk in gather
#define NTP 128  // nodes per projection block
#define KC 16    // K-chunk in projection
#define XST 133  // xt row stride: 133 mod 32 = 5 (coprime) -> conflict-free transposed writes

typedef float f4v __attribute__((ext_vector_type(4)));
typedef float f2v __attribute__((ext_vector_type(2)));

__device__ __forceinline__ float4 ntload4(const float* p) {
    f4v v = __builtin_nontemporal_load((const f4v*)p);
    return make_float4(v.x, v.y, v.z, v.w);
}
__device__ __forceinline__ void ntstore2(float* p, float a, float b) {
    f2v v = {a, b};
    __builtin_nontemporal_store(v, (f2v*)p);
}

// ==================== fused node projection + attention scalars ====================
// xt transposed [k][node] (stride 133), staged via COALESCED per-lane global loads +
// transposed ds_write_b32. wt [k][col] staged via global_load_lds width-16.
// 256 threads = 16 mg (8 nodes) x 16 cg (cols {cg*4, 64+cg*4}).
// Output XS is FP16 (halves the gather's random-read bytes); attention scalars stay FP32.
template <bool VEC4>
__global__ __launch_bounds__(256, 4) void node_proj_att(const float* __restrict__ X,
                                                        const float* __restrict__ W,
                                                        const float* __restrict__ att_src,
                                                        const float* __restrict__ att_dst,
                                                        __half* __restrict__ XSH,
                                                        float* __restrict__ asrc,
                                                        float* __restrict__ adst,
                                                        int K, long long maxx, long long maxw) {
    __shared__ float xt[2][KC][XST];  // transposed: [k][node]
    __shared__ float wt[2][KC][HID];
    int tid = threadIdx.x;
    int lane = tid & 63;
    int wv = tid >> 6;  // wave 0..3
    int block0 = blockIdx.x * NTP;
    int cg = tid & 15;
    int c0a = cg * 4, c0b = 64 + cg * 4;
    int mg = tid >> 4;  // 0..15
    int mbase = mg * 8;
    int nchunk = (K + KC - 1) / KC;

    float4 aA[8], aB[8];
#pragma unroll
    for (int m = 0; m < 8; ++m) {
        aA[m] = make_float4(0.f, 0.f, 0.f, 0.f);
        aB[m] = make_float4(0.f, 0.f, 0.f, 0.f);
    }

    float xreg[8];

    auto loadX = [&](int k0) {
        if (VEC4) {
#pragma unroll
            for (int i = 0; i < 2; ++i) {
                int row = wv * 32 + i * 16 + (lane >> 2);
                int k = (lane & 3) * 4;
                long long src = (long long)(block0 + row) * K + k0 + k;
                if (src > maxx - 3) src = maxx - 3;
                float4 v = *(const float4*)&X[src];
                xreg[i * 4 + 0] = v.x; xreg[i * 4 + 1] = v.y;
                xreg[i * 4 + 2] = v.z; xreg[i * 4 + 3] = v.w;
            }
        } else {
#pragma unroll
            for (int i = 0; i < 8; ++i) {
                int row = wv * 32 + i * 4 + (lane >> 4);
                long long src = (long long)(block0 + row) * K + k0 + (lane & 15);
                if (src > maxx) src = maxx;
                xreg[i] = X[src];
            }
        }
    };
    auto writeX = [&](int buf) {
        if (VEC4) {
#pragma unroll
            for (int i = 0; i < 2; ++i) {
                int row = wv * 32 + i * 16 + (lane >> 2);
                int k = (lane & 3) * 4;
#pragma unroll
                for (int j = 0; j < 4; ++j) xt[buf][k + j][row] = xreg[i * 4 + j];
            }
        } else {
#pragma unroll
            for (int i = 0; i < 8; ++i) {
                int row = wv * 32 + i * 4 + (lane >> 4);
                xt[buf][lane & 15][row] = xreg[i];
            }
        }
    };
    auto stageW = [&](int buf, int k0) {
#pragma unroll
        for (int i = 0; i < 2; ++i) {
            int idx = wv * 2 + i;  // 0..7, each instr covers 2 k-rows (1024B linear)
            long long src = (long long)(k0 + idx * 2) * HID + lane * 4;
            if (src > maxw - 3) src = maxw - 3;
            __builtin_amdgcn_global_load_lds(
                (const __attribute__((address_space(1))) void*)(W + src),
                (__attribute__((address_space(3))) void*)&wt[buf][idx * 2][0], 16, 0, 0);
        }
    };

    // prologue
    loadX(0);
    stageW(0, 0);
    asm volatile("s_waitcnt vmcnt(0)" ::: "memory");
    writeX(0);
    __syncthreads();

#define ROW8(m, xs)                                                              \
    aA[m].x += (xs)*w0.x; aA[m].y += (xs)*w0.y; aA[m].z += (xs)*w0.z; aA[m].w += (xs)*w0.w; \
    aB[m].x += (xs)*w1.x; aB[m].y += (xs)*w1.y; aB[m].z += (xs)*w1.z; aB[m].w += (xs)*w1.w;

    for (int c = 0; c < nchunk; ++c) {
        int k0 = c * KC;
        int cur = c & 1;
        bool more = (c + 1 < nchunk);
        if (more) { loadX(k0 + KC); stageW(cur ^ 1, k0 + KC); }
        int kc = min(KC, K - k0);
#pragma unroll 1
        for (int kk = 0; kk < kc; ++kk) {
            float4 x0 = *(const float4*)&xt[cur][kk][mbase];
            float4 x1 = *(const float4*)&xt[cur][kk][mbase + 4];
            float4 w0 = *(const float4*)&wt[cur][kk][c0a];
            float4 w1 = *(const float4*)&wt[cur][kk][c0b];
            ROW8(0, x0.x) ROW8(1, x0.y) ROW8(2, x0.z) ROW8(3, x0.w)
            ROW8(4, x1.x) ROW8(5, x1.y) ROW8(6, x1.z) ROW8(7, x1.w)
        }
        if (more) {
            asm volatile("s_waitcnt vmcnt(0)" ::: "memory");
            writeX(cur ^ 1);
        }
        __syncthreads();
    }
#undef ROW8

    // epilogue: write XS (fp16) + fused per-head attention dots (fp32).
    float4 ava = *(const float4*)&att_src[c0a];
    float4 avb = *(const float4*)&att_src[c0b];
    float4 bva = *(const float4*)&att_dst[c0a];
    float4 bvb = *(const float4*)&att_dst[c0b];
    int hA = cg >> 3, hB = 2 + (cg >> 3);
#pragma unroll
    for (int m = 0; m < 8; ++m) {
        int node = block0 + mbase + m;
        float sA = aA[m].x * ava.x + aA[m].y * ava.y + aA[m].z * ava.z + aA[m].w * ava.w;
        float sB = aB[m].x * avb.x + aB[m].y * avb.y + aB[m].z * avb.z + aB[m].w * avb.w;
        float dA = aA[m].x * bva.x + aA[m].y * bva.y + aA[m].z * bva.z + aA[m].w * bva.w;
        float dB = aB[m].x * bvb.x + aB[m].y * bvb.y + aB[m].z * bvb.z + aB[m].w * bvb.w;
        sA += __shfl_xor(sA, 1); sB += __shfl_xor(sB, 1);
        dA += __shfl_xor(dA, 1); dB += __shfl_xor(dB, 1);
        sA += __shfl_xor(sA, 2); sB += __shfl_xor(sB, 2);
        dA += __shfl_xor(dA, 2); dB += __shfl_xor(dB, 2);
        sA += __shfl_xor(sA, 4); sB += __shfl_xor(sB, 4);
        dA += __shfl_xor(dA, 4); dB += __shfl_xor(dB, 4);
        if (node < NN) {
            __half2 a01 = __floats2half2_rn(aA[m].x, aA[m].y);
            __half2 a23 = __floats2half2_rn(aA[m].z, aA[m].w);
            __half2 b01 = __floats2half2_rn(aB[m].x, aB[m].y);
            __half2 b23 = __floats2half2_rn(aB[m].z, aB[m].w);
            uint2 pa, pb;
            pa.x = *(unsigned*)&a01; pa.y = *(unsigned*)&a23;
            pb.x = *(unsigned*)&b01; pb.y = *(unsigned*)&b23;
            *(uint2*)&XSH[(size_t)node * HID + c0a] = pa;
            *(uint2*)&XSH[(size_t)node * HID + c0b] = pb;
            if ((cg & 7) == 0) {
                asrc[node * 4 + hA] = sA;
                asrc[node * 4 + hB] = sB;
                adst[node * 4 + hA] = dA;
                adst[node * 4 + hB] = dB;
            }
        }
    }
}

// ---- ve[d,h] = sum_c We[d, h*CH+c] * att_edge[h,c]  (8x4), both layers at once ----
__global__ void compute_ve2(const float* __restrict__ We1,
                            const float* __restrict__ ae1,
                            const float* __restrict__ We2,
                            const float* __restrict__ ae2,
                            float* __restrict__ ve1,
                            float* __restrict__ ve2) {
    int i = threadIdx.x;
    if (i >= 64) return;
    const float* We = (i < 32) ? We1 : We2;
    const float* ae = (i < 32) ? ae1 : ae2;
    float* ve = (i < 32) ? ve1 : ve2;
    int j = i & 31;
    int d = j >> 2, h = j & 3;
    float s = 0.f;
    for (int c = 0; c < CH; ++c) s += We[d * HID + h * CH + c] * ae[h * CH + c];
    ve[j] = s;
}

// ==================== CSR build ====================
__global__ __launch_bounds__(256) void k_deg(const int* __restrict__ ei, int* __restrict__ deg) {
    int e = blockIdx.x * 256 + threadIdx.x;
    if (e < NE) atomicAdd(&deg[ei[NE + e]], 1);
}

__global__ __launch_bounds__(256) void scan_local(const int* __restrict__ deg,
                                                  int* __restrict__ startv,
                                                  int* __restrict__ bsum) {
    __shared__ int sh[256];
    int t = threadIdx.x;
    int base = blockIdx.x * 1024 + t * 4;
    int v0 = 0, v1 = 0, v2 = 0, v3 = 0;
    if (base + 0 < NN) v0 = deg[base + 0];
    if (base + 1 < NN) v1 = deg[base + 1];
    if (base + 2 < NN) v2 = deg[base + 2];
    if (base + 3 < NN) v3 = deg[base + 3];
    int s1 = v0 + v1, s2 = s1 + v2, s3 = s2 + v3;
    sh[t] = s3;
    __syncthreads();
    for (int off = 1; off < 256; off <<= 1) {
        int x = (t >= off) ? sh[t - off] : 0;
        __syncthreads();
        sh[t] += x;
        __syncthreads();
    }
    int thOff = sh[t] - s3;  // exclusive
    if (base + 0 < NN) startv[base + 0] = thOff;
    if (base + 1 < NN) startv[base + 1] = thOff + v0;
    if (base + 2 < NN) startv[base + 2] = thOff + s1;
    if (base + 3 < NN) startv[base + 3] = thOff + s2;
    if (t == 255) bsum[blockIdx.x] = sh[255];
}

__global__ __launch_bounds__(256) void scan_bsum(int* __restrict__ bsum, int nb) {
    __shared__ int sh[256];
    int t = threadIdx.x;
    int v = (t < nb) ? bsum[t] : 0;
    sh[t] = v;
    __syncthreads();
    for (int off = 1; off < 256; off <<= 1) {
        int x = (t >= off) ? sh[t - off] : 0;
        __syncthreads();
        sh[t] += x;
        __syncthreads();
    }
    if (t < nb) bsum[t] = sh[t] - v;  // exclusive
}

__global__ __launch_bounds__(256) void scan_add(int* __restrict__ startv,
                                                const int* __restrict__ bsum) {
    int i = blockIdx.x * 256 + threadIdx.x;
    if (i < NN) startv[i] += bsum[i >> 10];
}

// scatter: permute src index AND precompute both layers' a_edge dots (32B record).
__global__ __launch_bounds__(256) void k_scatter(const int* __restrict__ ei,
                                                 const int* __restrict__ startv,
                                                 int* __restrict__ cursor,
                                                 const float* __restrict__ eattr,
                                                 const float* __restrict__ ve1,
                                                 const float* __restrict__ ve2,
                                                 int* __restrict__ srcperm,
                                                 float* __restrict__ aeP12) {
    __shared__ float v1[32], v2[32];
    if (threadIdx.x < 32) v1[threadIdx.x] = ve1[threadIdx.x];
    else if (threadIdx.x < 64) v2[threadIdx.x - 32] = ve2[threadIdx.x - 32];
    __syncthreads();
    int e = blockIdx.x * 256 + threadIdx.x;
    if (e >= NE) return;
    int d = ei[NE + e];
    float4 e0 = *(const float4*)&eattr[(size_t)e * 8];
    float4 e1 = *(const float4*)&eattr[(size_t)e * 8 + 4];
    float eav[8] = {e0.x, e0.y, e0.z, e0.w, e1.x, e1.y, e1.z, e1.w};
    float a1[4], a2[4];
#pragma unroll
    for (int hh = 0; hh < 4; ++hh) {
        float s1 = 0.f, s2 = 0.f;
#pragma unroll
        for (int dd = 0; dd < 8; ++dd) {
            s1 += eav[dd] * v1[dd * 4 + hh];
            s2 += eav[dd] * v2[dd * 4 + hh];
        }
        a1[hh] = s1;
        a2[hh] = s2;
    }
    int pos = startv[d] + atomicAdd(&cursor[d], 1);
    srcperm[pos] = ei[e];
    *(float4*)&aeP12[(size_t)pos * 8] = make_float4(a1[0], a1[1], a1[2], a1[3]);
    *(float4*)&aeP12[(size_t)pos * 8 + 4] = make_float4(a2[0], a2[1], a2[2], a2[3]);
}

// ==================== fused gather: softmax (no-max) + aggregate + bias + relu ====
// one wave per dst node. Stage reads srcperm (nt) + aeP half-record (nt) + asrc[s]
// (cached); p = exp(leaky(as+ad+ae)). XS is FP16: 256B per edge-row (half the bytes).
// Sweep keeps 8 XS row-gathers in flight.
__global__ __launch_bounds__(256) void gat_gather(const int* __restrict__ startv,
                                                  const int* __restrict__ deg,
                                                  const int* __restrict__ srcperm,
                                                  const float* __restrict__ aeL,  // aeP12 + layer*4
                                                  const float* __restrict__ asrc,
                                                  const float* __restrict__ adst,
                                                  const __half* __restrict__ XSH,
                                                  const float* __restrict__ bias,
                                                  float* __restrict__ OUT) {
    __shared__ float s_p[4][CHK * 4];
    __shared__ int s_src[4][CHK];
    int w = threadIdx.x >> 6;
    int wid = blockIdx.x * 4 + w;
    if (wid >= NN) return;
    int lane = threadIdx.x & 63;
    int s0 = startv[wid];
    int dg = deg[wid];
    float4 ad4 = *(const float4*)&adst[wid * 4];
    int h = lane >> 4;
    int c0 = lane * 2;

    float denom = 0.f, acc0 = 0.f, acc1 = 0.f;

    for (int cb = 0; cb < dg; cb += CHK) {
        int cnt = min(CHK, dg - cb);
        // stage: src index + per-head p = exp(alpha) into LDS (wave-synchronous)
        for (int i = lane; i < cnt; i += 64) {
            int pos = s0 + cb + i;
            int s = __builtin_nontemporal_load(&srcperm[pos]);
            s_src[w][i] = s;
            float4 ae = ntload4(&aeL[(size_t)pos * 8]);
            float4 as4 = *(const float4*)&asrc[s * 4];
            float a0 = as4.x + ad4.x + ae.x;
            float a1 = as4.y + ad4.y + ae.y;
            float a2 = as4.z + ad4.z + ae.z;
            float a3 = as4.w + ad4.w + ae.w;
            a0 = (a0 > 0.f) ? a0 : 0.2f * a0;
            a1 = (a1 > 0.f) ? a1 : 0.2f * a1;
            a2 = (a2 > 0.f) ? a2 : 0.2f * a2;
            a3 = (a3 > 0.f) ? a3 : 0.2f * a3;
            *(float4*)&s_p[w][i * 4] =
                make_float4(__expf(a0), __expf(a1), __expf(a2), __expf(a3));
        }
        // accumulate sweep, 8 XS gathers in flight
        int j = 0;
        for (; j + 7 < cnt; j += 8) {
            int sv[8];
            float pv[8];
            __half2 xv[8];
#pragma unroll
            for (int q = 0; q < 8; ++q) {
                sv[q] = s_src[w][j + q];
                pv[q] = s_p[w][(j + q) * 4 + h];
            }
#pragma unroll
            for (int q = 0; q < 8; ++q) xv[q] = *(const __half2*)&XSH[(size_t)sv[q] * HID + c0];
#pragma unroll
            for (int q = 0; q < 8; ++q) {
                float2 xf = __half22float2(xv[q]);
                denom += pv[q];
                acc0 += pv[q] * xf.x;
                acc1 += pv[q] * xf.y;
            }
        }
        for (; j < cnt; ++j) {
            int s = s_src[w][j];
            float p = s_p[w][j * 4 + h];
            float2 xf = __half22float2(*(const __half2*)&XSH[(size_t)s * HID + c0]);
            denom += p;
            acc0 += p * xf.x;
            acc1 += p * xf.y;
        }
    }
    float inv = 1.f / (denom + 1e-16f);
    float2 bv = *(const float2*)&bias[c0];
    float o0 = fmaxf(acc0 * inv + bv.x, 0.f);
    float o1 = fmaxf(acc1 * inv + bv.y, 0.f);
    ntstore2(&OUT[(size_t)wid * HID + c0], o0, o1);
}

// ==================== pooling ====================
#define POOL_CHUNK 512
__global__ __launch_bounds__(256) void pool_kernel(const float* __restrict__ H,
                                                   const int* __restrict__ batch,
                                                   float* __restrict__ pooled,
                                                   float* __restrict__ counts) {
    __shared__ float tab[64 * HID];
    __shared__ float cnt[64];
    int tid = threadIdx.x;
    int n0 = blockIdx.x * POOL_CHUNK;
    int nmax = min(POOL_CHUNK, NN - n0);
    for (int i = tid; i < 64 * HID; i += 256) tab[i] = 0.f;
    if (tid < 64) cnt[tid] = 0.f;
    __syncthreads();
    for (int i = tid; i < nmax * HID; i += 256) {
        int n = n0 + (i >> 7), c = i & 127;
        int g = batch[n];
        atomicAdd(&tab[g * HID + c], H[(long long)n * HID + c]);
    }
    for (int n = tid; n < nmax; n += 256) atomicAdd(&cnt[batch[n0 + n]], 1.f);
    __syncthreads();
    int gmin = batch[n0], gmax = batch[n0 + nmax - 1];
    int ng = gmax - gmin + 1;
    for (int i = tid; i < ng * HID; i += 256) {
        int g = gmin + (i >> 7), c = i & 127;
        atomicAdd(&pooled[g * HID + c], tab[g * HID + c]);
    }
    if (tid < ng) atomicAdd(&counts[gmin + tid], cnt[gmin + tid]);
}

// ==================== classifier ====================
__global__ __launch_bounds__(64) void classifier(const float* __restrict__ pooled,
                                                 const float* __restrict__ counts,
                                                 const float* __restrict__ Wc1,
                                                 const float* __restrict__ bc1,
                                                 const float* __restrict__ Wc2,
                                                 const float* __restrict__ bc2,
                                                 float* __restrict__ out) {
    __shared__ float pl[HID];
    __shared__ float z[64];
    int g = blockIdx.x, t = threadIdx.x;
    float inv = 1.f / fmaxf(counts[g], 1.f);
    pl[t] = pooled[g * HID + t] * inv;
    pl[t + 64] = pooled[g * HID + 64 + t] * inv;
    __syncthreads();
    float a = bc1[t];
    for (int k = 0; k < HID; ++k) a += pl[k] * Wc1[k * 64 + t];
    z[t] = fmaxf(a, 0.f);
    __syncthreads();
    if (t < 2) {
        float o = bc2[t];
        for (int j = 0; j < 64; ++j) o += z[j] * Wc2[j * 2 + t];
        out[g * 2 + t] = o;
    }
}

extern "C" void kernel_launch(void* const* d_in, const int* in_sizes, int n_in,
                              void* d_out, int out_size, void* d_ws, size_t ws_size,
                              hipStream_t stream) {
    const float* x = (const float*)d_in[0];
    const int* ei = (const int*)d_in[1];
    const float* eattr = (const float*)d_in[2];
    const int* batch = (const int*)d_in[3];
    const float* W1 = (const float*)d_in[4];
    const float* att_src1 = (const float*)d_in[5];
    const float* att_dst1 = (const float*)d_in[6];
    const float* We1 = (const float*)d_in[7];
    const float* att_edge1 = (const float*)d_in[8];
    const float* b1 = (const float*)d_in[9];
    const float* W2 = (const float*)d_in[10];
    const float* att_src2 = (const float*)d_in[11];
    const float* att_dst2 = (const float*)d_in[12];
    const float* We2 = (const float*)d_in[13];
    const float* att_edge2 = (const float*)d_in[14];
    const float* b2 = (const float*)d_in[15];
    const float* Wc1 = (const float*)d_in[16];
    const float* bc1 = (const float*)d_in[17];
    const float* Wc2 = (const float*)d_in[18];
    const float* bc2 = (const float*)d_in[19];
    float* out = (float*)d_out;

    // workspace layout
    __half* XSH = (__half*)d_ws;                    // xs buffer [N,128] fp16 (25.6MB)
    float* B = (float*)(XSH + (size_t)NN * HID);    // h buffer [N,128] fp32
    float* asrc = B + (size_t)NN * HID;             // [N,4]
    float* adst = asrc + (size_t)NN * 4;            // [N,4]
    float* ve1 = adst + (size_t)NN * 4;             // [32]
    float* ve2 = ve1 + 32;                          // [32]
    float* pooled = ve2 + 32;                       // [64,128]
    float* counts = pooled + 64 * HID;              // [64]
    float* aeP12 = counts + 64;                     // [E,8] permuted {ae1[4], ae2[4]}
    int* deg = (int*)(aeP12 + (size_t)NE * 8);      // [N]
    int* cursor = deg + NN;                         // [N]
    int* startv = cursor + NN;                      // [N]
    int* bsum = startv + NN;                        // [256]
    int* srcperm = bsum + 256;                      // [E]

    int gProj = (NN + NTP - 1) / NTP;  // 782
    int gE = (NE + 255) / 256;
    int gGat = (NN + 3) / 4;
    int nScanBlk = (NN + 1023) / 1024;  // 98

    // ===== CSR build + edge permutation (once per launch) =====
    hipMemsetAsync(deg, 0, (size_t)2 * NN * sizeof(int), stream);  // deg + cursor
    compute_ve2<<<1, 64, 0, stream>>>(We1, att_edge1, We2, att_edge2, ve1, ve2);
    k_deg<<<gE, 256, 0, stream>>>(ei, deg);
    scan_local<<<nScanBlk, 256, 0, stream>>>(deg, startv, bsum);
    scan_bsum<<<1, 256, 0, stream>>>(bsum, nScanBlk);
    scan_add<<<(NN + 255) / 256, 256, 0, stream>>>(startv, bsum);
    k_scatter<<<gE, 256, 0, stream>>>(ei, startv, cursor, eattr, ve1, ve2, srcperm, aeP12);

    // ===== layer 1 =====
    node_proj_att<false><<<gProj, 256, 0, stream>>>(x, W1, att_src1, att_dst1, XSH, asrc, adst,
                                                    IN_DIM, (long long)NN * IN_DIM - 1,
                                                    (long long)IN_DIM * HID - 1);
    gat_gather<<<gGat, 256, 0, stream>>>(startv, deg, srcperm, aeP12, asrc, adst,
                                         XSH, b1, B);  // B = h1

    // ===== layer 2 =====
    node_proj_att<true><<<gProj, 256, 0, stream>>>(B, W2, att_src2, att_dst2, XSH, asrc, adst,
                                                   HID, (long long)NN * HID - 1,
                                                   (long long)HID * HID - 1);
    gat_gather<<<gGat, 256, 0, stream>>>(startv, deg, srcperm, aeP12 + 4, asrc, adst,
                                         XSH, b2, B);  // B = h2

    // ===== pool + classify =====
    hipMemsetAsync(pooled, 0, (64 * HID + 64) * sizeof(float), stream);
    pool_kernel<<<(NN + POOL_CHUNK - 1) / POOL_CHUNK, 256, 0, stream>>>(B, batch, pooled, counts);
    classifier<<<64, 64, 0, stream>>>(pooled, counts, Wc1, bc1, Wc2, bc2, out);
}